// Round 1
// baseline (1038.658 us; speedup 1.0000x reference)
//
#include <hip/hip_runtime.h>

// ---------------------------------------------------------------------------
// capsule_87840671138361: conv->routing->attention->fusion, MI355X (gfx950)
// Pipeline:
//   1) conv_route: causal depthwise conv k=3/5 + 2x dynamic routing (fp32,
//      wave-per-position), writes v_seasonal/v_trend as bf16 row-major AND
//      channel-major (vT) copies for the attention kernel.
//   2) attn: flash-style causal attention with -DECAY*dist bias, bf16 MFMA
//      16x16x32. 64 queries/block (16/wave), 32 keys/iter. Q in registers,
//      QK^T B-frags direct from global (L1/L2), V from LDS (channel-major),
//      P via LDS round-trip (C-layout -> A-layout). Writes bf16 into cat.
//   3) fusion_gemm: [16384,1024]x[1024,512]^T bf16 MFMA 128x128 tiles + bias.
// ---------------------------------------------------------------------------

typedef short     bf16x8 __attribute__((ext_vector_type(8)));  // MFMA A/B frag (guide-verified short8)
typedef float     f32x4  __attribute__((ext_vector_type(4)));  // MFMA C/D frag
typedef unsigned short u16;
typedef u16       u16x8  __attribute__((ext_vector_type(8)));
typedef u16       u16x4  __attribute__((ext_vector_type(4)));

#define NBATCH 8
#define LSEQ   2048
#define DCH    512
#define DECAYF 0.2f

__device__ __forceinline__ u16 f2bf(float f) {
    unsigned int u = __float_as_uint(f);
    u += 0x7fffu + ((u >> 16) & 1u);   // RNE; inputs never NaN
    return (u16)(u >> 16);
}

__device__ __forceinline__ float wave_sum(float v) {
#pragma unroll
    for (int m = 1; m < 64; m <<= 1) v += __shfl_xor(v, m, 64);
    return v;
}

// ---------------------------------------------------------------------------
// Kernel 1: fused causal depthwise conv (k=3,5) + dynamic routing (3 iters)
// One wave per (n,l): lane owns 8 channels; reductions = wave shuffles.
// ---------------------------------------------------------------------------
__device__ __forceinline__ void route2(const float* u0, const float* u1, float* vout) {
    float b0 = 0.f, b1 = 0.f;
#pragma unroll
    for (int it = 0; it < 3; ++it) {
        float mx  = fmaxf(b0, b1);
        float e0  = __expf(b0 - mx), e1 = __expf(b1 - mx);
        float inv = 1.f / (e0 + e1);
        float c0 = e0 * inv, c1 = e1 * inv;
        float n2 = 0.f;
        float s[8];
#pragma unroll
        for (int i = 0; i < 8; ++i) { s[i] = c0*u0[i] + c1*u1[i]; n2 += s[i]*s[i]; }
        n2 = wave_sum(n2);
        float nrm = sqrtf(n2);
        float sc  = n2 / ((1.f + n2) * (nrm + 1e-9f));   // squash scale
#pragma unroll
        for (int i = 0; i < 8; ++i) vout[i] = sc * s[i];
        if (it < 2) {
            float d0 = 0.f, d1 = 0.f;
#pragma unroll
            for (int i = 0; i < 8; ++i) { d0 += u0[i]*vout[i]; d1 += u1[i]*vout[i]; }
            d0 = wave_sum(d0); d1 = wave_sum(d1);
            b0 += d0; b1 += d1;
        }
    }
}

__global__ __launch_bounds__(256) void conv_route(
    const float* __restrict__ x, const float* __restrict__ w3, const float* __restrict__ w5,
    u16* __restrict__ vs, u16* __restrict__ vt,
    u16* __restrict__ vsT, u16* __restrict__ vtT)
{
    const int wid  = threadIdx.x >> 6;
    const int lane = threadIdx.x & 63;
    const int p = blockIdx.x * 4 + wid;          // 16384 positions
    const int n = p >> 11, l = p & (LSEQ - 1);
    const int c0 = lane * 8;

    float xm[5][8];                              // xm[j][i] = x[l-j][c0+i]
#pragma unroll
    for (int j = 0; j < 5; ++j) {
        int ll = l - j;
        if (ll >= 0) {
            const float4* sp = (const float4*)(x + ((size_t)(n*LSEQ + ll))*DCH + c0);
            float4 a = sp[0], b = sp[1];
            xm[j][0]=a.x; xm[j][1]=a.y; xm[j][2]=a.z; xm[j][3]=a.w;
            xm[j][4]=b.x; xm[j][5]=b.y; xm[j][6]=b.z; xm[j][7]=b.w;
        } else {
#pragma unroll
            for (int i = 0; i < 8; ++i) xm[j][i] = 0.f;
        }
    }
    float f3[24], f5[40];
#pragma unroll
    for (int k = 0; k < 6; ++k)  ((float4*)f3)[k] = ((const float4*)(w3 + (size_t)c0*3))[k];
#pragma unroll
    for (int k = 0; k < 10; ++k) ((float4*)f5)[k] = ((const float4*)(w5 + (size_t)c0*5))[k];

    // causal conv: y[l] = sum_j w[j]*x[l-(k-1)+j]
    float t3[8], t5[8], u0[8], u1[8], vv[8];
#pragma unroll
    for (int i = 0; i < 8; ++i) {
        t3[i] = f3[i*3+0]*xm[2][i] + f3[i*3+1]*xm[1][i] + f3[i*3+2]*xm[0][i];
        t5[i] = f5[i*5+0]*xm[4][i] + f5[i*5+1]*xm[3][i] + f5[i*5+2]*xm[2][i]
              + f5[i*5+3]*xm[1][i] + f5[i*5+4]*xm[0][i];
    }

    // seasonal routing: u = [x - t3, x - t5]
#pragma unroll
    for (int i = 0; i < 8; ++i) { u0[i] = xm[0][i] - t3[i]; u1[i] = xm[0][i] - t5[i]; }
    route2(u0, u1, vv);
    {
        u16x8 pk;
#pragma unroll
        for (int i = 0; i < 8; ++i) pk[i] = f2bf(vv[i]);
        *(u16x8*)(vs + (size_t)p*DCH + c0) = pk;
#pragma unroll
        for (int i = 0; i < 8; ++i) vsT[((size_t)(n*DCH + c0 + i))*LSEQ + l] = pk[i];
    }
    // trend routing: u = [t3, t5]
    route2(t3, t5, vv);
    {
        u16x8 pk;
#pragma unroll
        for (int i = 0; i < 8; ++i) pk[i] = f2bf(vv[i]);
        *(u16x8*)(vt + (size_t)p*DCH + c0) = pk;
#pragma unroll
        for (int i = 0; i < 8; ++i) vtT[((size_t)(n*DCH + c0 + i))*LSEQ + l] = pk[i];
    }
}

// ---------------------------------------------------------------------------
// Kernel 2: causal attention with exp(-decay*dist) bias, online softmax.
// grid (32 row-blocks, 16 instances), 256 threads (4 waves).
// Wave w owns query rows r0+16w..+15. BN=32 keys/iter.
// ---------------------------------------------------------------------------
__global__ __launch_bounds__(256) void attn(
    const u16* __restrict__ vs, const u16* __restrict__ vt,
    const u16* __restrict__ vsT, const u16* __restrict__ vtT,
    u16* __restrict__ cat)
{
    __shared__ u16 Kt[512][40];    // V tile, channel-major [c][key], pad->40 (stride 80B: 2-way banks)
    __shared__ u16 Ps[4][16][40];  // per-wave P [local row][key]

    const int inst = blockIdx.y;
    const int t = inst >> 3, n = inst & 7;
    const u16* src  = (t ? vt  : vs)  + (size_t)n * LSEQ * DCH;
    const u16* srcT = (t ? vtT : vsT) + (size_t)n * DCH * LSEQ;

    // big/small row-tile pairing for causal load balance
    const int rbx = blockIdx.x;
    const int rb  = (rbx & 1) ? (31 - (rbx >> 1)) : (rbx >> 1);
    const int r0  = rb * 64;

    const int tid  = threadIdx.x;
    const int wid  = tid >> 6, lane = tid & 63;
    const int l16  = lane & 15, quad = lane >> 4;

    // Q A-frags register-resident: lane holds Q[row=r0+16w+l16][kc*32+quad*8 ..+7]
    bf16x8 qf[16];
    {
        const u16* qp = src + (size_t)(r0 + wid*16 + l16) * DCH + quad*8;
#pragma unroll
        for (int kc = 0; kc < 16; ++kc) qf[kc] = *(const bf16x8*)(qp + kc*32);
    }

    f32x4 O[32];
#pragma unroll
    for (int i = 0; i < 32; ++i) O[i] = (f32x4){0.f, 0.f, 0.f, 0.f};
    float m_old[4] = {-__builtin_inff(), -__builtin_inff(), -__builtin_inff(), -__builtin_inff()};
    float l_run[4] = {0.f, 0.f, 0.f, 0.f};

    const int nkb = (r0 >> 5) + 2;   // key tiles up to (and incl.) diagonal
    for (int kb = 0; kb < nkb; ++kb) {
        // stage V tile channel-major from pre-transposed global vT
#pragma unroll
        for (int i = 0; i < 8; ++i) {
            int id = tid + i*256;            // 2048 chunks of 8
            int c = id >> 2, k2 = id & 3;
            *(u16x8*)(&Kt[c][k2*8]) = *(const u16x8*)(srcT + (size_t)c*LSEQ + kb*32 + k2*8);
        }
        __syncthreads();

        // Phase A: S[16x32] = Q * K^T ; B-frags straight from global (L1/L2)
        f32x4 S0 = {0.f,0.f,0.f,0.f}, S1 = {0.f,0.f,0.f,0.f};
        {
            const u16* kB = src + (size_t)(kb*32 + l16) * DCH + quad*8;
#pragma unroll
            for (int kc = 0; kc < 16; ++kc) {
                bf16x8 b0 = *(const bf16x8*)(kB + kc*32);
                bf16x8 b1 = *(const bf16x8*)(kB + 16*DCH + kc*32);
                S0 = __builtin_amdgcn_mfma_f32_16x16x32_bf16(qf[kc], b0, S0, 0, 0, 0);
                S1 = __builtin_amdgcn_mfma_f32_16x16x32_bf16(qf[kc], b1, S1, 0, 0, 0);
            }
        }

        // online softmax (C-layout: row = quad*4+r, col/key = l16 within tile)
        float al[4];
        const int rowg = r0 + wid*16 + quad*4;
#pragma unroll
        for (int r = 0; r < 4; ++r) {
            int row = rowg + r;
            int d0  = row - (kb*32 + l16);   // dist to tile0 key
            int d1  = d0 - 16;               // dist to tile1 key
            float s0 = (d0 >= 0) ? (S0[r] - DECAYF * (float)d0) : -__builtin_inff();
            float s1 = (d1 >= 0) ? (S1[r] - DECAYF * (float)d1) : -__builtin_inff();
            float rm = fmaxf(s0, s1);
            rm = fmaxf(rm, __shfl_xor(rm, 1, 64));
            rm = fmaxf(rm, __shfl_xor(rm, 2, 64));
            rm = fmaxf(rm, __shfl_xor(rm, 4, 64));
            rm = fmaxf(rm, __shfl_xor(rm, 8, 64));
            float mn = fmaxf(m_old[r], rm);
            float a  = __expf(m_old[r] - mn);    // first iter: exp(-inf)=0
            m_old[r] = mn;
            float p0 = __expf(s0 - mn);
            float p1 = __expf(s1 - mn);
            Ps[wid][quad*4 + r][l16]      = f2bf(p0);
            Ps[wid][quad*4 + r][16 + l16] = f2bf(p1);
            float rs = p0 + p1;
            rs += __shfl_xor(rs, 1, 64);
            rs += __shfl_xor(rs, 2, 64);
            rs += __shfl_xor(rs, 4, 64);
            rs += __shfl_xor(rs, 8, 64);
            l_run[r] = l_run[r] * a + rs;
            al[r] = a;
        }
#pragma unroll
        for (int ct = 0; ct < 32; ++ct) {
            O[ct][0] *= al[0]; O[ct][1] *= al[1]; O[ct][2] *= al[2]; O[ct][3] *= al[3];
        }

        // Phase B: O[16x512] += P[16x32] * V[32x512]; P A-frag via LDS round-trip
        bf16x8 pf = *(const bf16x8*)(&Ps[wid][l16][quad*8]);
#pragma unroll
        for (int ct = 0; ct < 32; ++ct) {
            bf16x8 vf = *(const bf16x8*)(&Kt[ct*16 + l16][quad*8]);
            O[ct] = __builtin_amdgcn_mfma_f32_16x16x32_bf16(pf, vf, O[ct], 0, 0, 0);
        }
        __syncthreads();   // protect Kt before next stage
    }

    // epilogue: O /= l, write bf16 into cat (seasonal: cols 0-511, trend: 512-1023)
    float inv[4];
#pragma unroll
    for (int r = 0; r < 4; ++r) inv[r] = 1.f / l_run[r];
    const size_t rowbase = (size_t)n * LSEQ + r0 + wid*16 + quad*4;
    const int colbase = t * 512 + l16;
#pragma unroll
    for (int ct = 0; ct < 32; ++ct) {
#pragma unroll
        for (int r = 0; r < 4; ++r)
            cat[(rowbase + r) * 1024 + colbase + ct*16] = f2bf(O[ct][r] * inv[r]);
    }
}

// ---------------------------------------------------------------------------
// Kernel 3: cast fusion_w fp32 -> bf16
// ---------------------------------------------------------------------------
__global__ __launch_bounds__(256) void cast_w(const float* __restrict__ w, u16* __restrict__ wb)
{
    int id = blockIdx.x * 256 + threadIdx.x;   // 131072 float4 chunks
    float4 f = ((const float4*)w)[id];
    u16x4 o;
    o[0] = f2bf(f.x); o[1] = f2bf(f.y); o[2] = f2bf(f.z); o[3] = f2bf(f.w);
    ((u16x4*)wb)[id] = o;
}

// ---------------------------------------------------------------------------
// Kernel 4: out[16384,512] = cat[16384,1024] @ W[512,1024]^T + bias (fp32 out)
// 128x128 tiles, BK=64, 4 waves each 64x64 (4x4 of 16x16x32 MFMA).
// ---------------------------------------------------------------------------
__global__ __launch_bounds__(256) void fusion_gemm(
    const u16* __restrict__ A, const u16* __restrict__ B,
    const float* __restrict__ bias, float* __restrict__ out)
{
    __shared__ u16 As[128][72];
    __shared__ u16 Bs[128][72];
    const int m0 = blockIdx.x * 128;
    const int n0 = blockIdx.y * 128;
    const int tid = threadIdx.x;
    const int wid = tid >> 6, lane = tid & 63;
    const int l16 = lane & 15, quad = lane >> 4;
    const int wm = (wid >> 1) * 64, wn = (wid & 1) * 64;

    f32x4 acc[4][4];
#pragma unroll
    for (int i = 0; i < 4; ++i)
#pragma unroll
        for (int j = 0; j < 4; ++j) acc[i][j] = (f32x4){0.f, 0.f, 0.f, 0.f};

    for (int kb = 0; kb < 16; ++kb) {
#pragma unroll
        for (int i = 0; i < 4; ++i) {
            int id = tid + i*256;            // 1024 chunks of 8
            int row = id >> 3, kc = id & 7;
            *(u16x8*)(&As[row][kc*8]) = *(const u16x8*)(A + (size_t)(m0+row)*1024 + kb*64 + kc*8);
            *(u16x8*)(&Bs[row][kc*8]) = *(const u16x8*)(B + (size_t)(n0+row)*1024 + kb*64 + kc*8);
        }
        __syncthreads();
#pragma unroll
        for (int k2 = 0; k2 < 2; ++k2) {
            bf16x8 af[4], bf[4];
#pragma unroll
            for (int i = 0; i < 4; ++i) {
                af[i] = *(const bf16x8*)(&As[wm + i*16 + l16][k2*32 + quad*8]);
                bf[i] = *(const bf16x8*)(&Bs[wn + i*16 + l16][k2*32 + quad*8]);
            }
#pragma unroll
            for (int i = 0; i < 4; ++i)
#pragma unroll
                for (int j = 0; j < 4; ++j)
                    acc[i][j] = __builtin_amdgcn_mfma_f32_16x16x32_bf16(af[i], bf[j], acc[i][j], 0, 0, 0);
        }
        __syncthreads();
    }
#pragma unroll
    for (int j = 0; j < 4; ++j) {
        int col = n0 + wn + j*16 + l16;
        float bv = bias[col];
#pragma unroll
        for (int i = 0; i < 4; ++i) {
            int rowb = m0 + wm + i*16 + quad*4;
#pragma unroll
            for (int r = 0; r < 4; ++r)
                out[(size_t)(rowb + r)*512 + col] = acc[i][j][r] + bv;
        }
    }
}

// ---------------------------------------------------------------------------
extern "C" void kernel_launch(void* const* d_in, const int* in_sizes, int n_in,
                              void* d_out, int out_size, void* d_ws, size_t ws_size,
                              hipStream_t stream)
{
    (void)in_sizes; (void)n_in; (void)out_size; (void)ws_size;
    const float* x  = (const float*)d_in[0];
    const float* w3 = (const float*)d_in[1];
    const float* w5 = (const float*)d_in[2];
    const float* fw = (const float*)d_in[3];
    const float* fb = (const float*)d_in[4];
    float* out = (float*)d_out;

    const size_t SZ = (size_t)NBATCH * LSEQ * DCH;   // 8.39M elements
    u16* vs  = (u16*)d_ws;      // [N,L,D] bf16
    u16* vt  = vs  + SZ;
    u16* vsT = vt  + SZ;        // [N,D,L] bf16
    u16* vtT = vsT + SZ;
    u16* cat = vtT + SZ;        // [N*L, 1024] bf16
    u16* wb  = cat + 2*SZ;      // [512,1024] bf16
    // total ws: ~102 MB

    cast_w    <<<512, 256, 0, stream>>>(fw, wb);
    conv_route<<<4096, 256, 0, stream>>>(x, w3, w5, vs, vt, vsT, vtT);
    attn      <<<dim3(32, 16), 256, 0, stream>>>(vs, vt, vsT, vtT, cat);
    fusion_gemm<<<dim3(128, 4), 256, 0, stream>>>(cat, wb, fb, out);
}

// Round 2
// 381.201 us; speedup vs baseline: 2.7247x; 2.7247x over previous
//
#include <hip/hip_runtime.h>

// ---------------------------------------------------------------------------
// capsule_87840671138361: conv->routing->attention->fusion, MI355X (gfx950)
// R2 changes vs R1:
//  - attn: decay-justified 192-key window (8 tiles of 32) -> uniform work per
//    block (kills 2..64-iter imbalance; truncation error ~3e-16 << 3e-3 thr).
//  - attn: barrier-free. V B-frags read straight from transposed global vT
//    (L2-resident); only per-wave Ps LDS round-trip remains (wave-coherent).
//  - conv_route no longer scatters vT (2B stores @4KB stride); dedicated
//    LDS-tiled transpose kernel writes vsT/vtT coalesced.
// ---------------------------------------------------------------------------

typedef short     bf16x8 __attribute__((ext_vector_type(8)));  // MFMA A/B frag
typedef float     f32x4  __attribute__((ext_vector_type(4)));  // MFMA C/D frag
typedef unsigned short u16;
typedef u16       u16x8  __attribute__((ext_vector_type(8)));
typedef u16       u16x4  __attribute__((ext_vector_type(4)));

#define NBATCH 8
#define LSEQ   2048
#define DCH    512
#define DECAYF 0.2f
#define WTILES 8   // window = 8 key-tiles of 32 = 256-key span (>=192 per query)

__device__ __forceinline__ u16 f2bf(float f) {
    unsigned int u = __float_as_uint(f);
    u += 0x7fffu + ((u >> 16) & 1u);   // RNE; inputs never NaN
    return (u16)(u >> 16);
}

__device__ __forceinline__ float wave_sum(float v) {
#pragma unroll
    for (int m = 1; m < 64; m <<= 1) v += __shfl_xor(v, m, 64);
    return v;
}

// ---------------------------------------------------------------------------
// Kernel 1: fused causal depthwise conv (k=3,5) + dynamic routing (3 iters)
// One wave per (n,l): lane owns 8 channels; reductions = wave shuffles.
// ---------------------------------------------------------------------------
__device__ __forceinline__ void route2(const float* u0, const float* u1, float* vout) {
    float b0 = 0.f, b1 = 0.f;
#pragma unroll
    for (int it = 0; it < 3; ++it) {
        float mx  = fmaxf(b0, b1);
        float e0  = __expf(b0 - mx), e1 = __expf(b1 - mx);
        float inv = 1.f / (e0 + e1);
        float c0 = e0 * inv, c1 = e1 * inv;
        float n2 = 0.f;
        float s[8];
#pragma unroll
        for (int i = 0; i < 8; ++i) { s[i] = c0*u0[i] + c1*u1[i]; n2 += s[i]*s[i]; }
        n2 = wave_sum(n2);
        float nrm = sqrtf(n2);
        float sc  = n2 / ((1.f + n2) * (nrm + 1e-9f));   // squash scale
#pragma unroll
        for (int i = 0; i < 8; ++i) vout[i] = sc * s[i];
        if (it < 2) {
            float d0 = 0.f, d1 = 0.f;
#pragma unroll
            for (int i = 0; i < 8; ++i) { d0 += u0[i]*vout[i]; d1 += u1[i]*vout[i]; }
            d0 = wave_sum(d0); d1 = wave_sum(d1);
            b0 += d0; b1 += d1;
        }
    }
}

__global__ __launch_bounds__(256) void conv_route(
    const float* __restrict__ x, const float* __restrict__ w3, const float* __restrict__ w5,
    u16* __restrict__ vs, u16* __restrict__ vt)
{
    const int wid  = threadIdx.x >> 6;
    const int lane = threadIdx.x & 63;
    const int p = blockIdx.x * 4 + wid;          // 16384 positions
    const int n = p >> 11, l = p & (LSEQ - 1);
    const int c0 = lane * 8;

    float xm[5][8];                              // xm[j][i] = x[l-j][c0+i]
#pragma unroll
    for (int j = 0; j < 5; ++j) {
        int ll = l - j;
        if (ll >= 0) {
            const float4* sp = (const float4*)(x + ((size_t)(n*LSEQ + ll))*DCH + c0);
            float4 a = sp[0], b = sp[1];
            xm[j][0]=a.x; xm[j][1]=a.y; xm[j][2]=a.z; xm[j][3]=a.w;
            xm[j][4]=b.x; xm[j][5]=b.y; xm[j][6]=b.z; xm[j][7]=b.w;
        } else {
#pragma unroll
            for (int i = 0; i < 8; ++i) xm[j][i] = 0.f;
        }
    }
    float f3[24], f5[40];
#pragma unroll
    for (int k = 0; k < 6; ++k)  ((float4*)f3)[k] = ((const float4*)(w3 + (size_t)c0*3))[k];
#pragma unroll
    for (int k = 0; k < 10; ++k) ((float4*)f5)[k] = ((const float4*)(w5 + (size_t)c0*5))[k];

    float t3[8], t5[8], u0[8], u1[8], vv[8];
#pragma unroll
    for (int i = 0; i < 8; ++i) {
        t3[i] = f3[i*3+0]*xm[2][i] + f3[i*3+1]*xm[1][i] + f3[i*3+2]*xm[0][i];
        t5[i] = f5[i*5+0]*xm[4][i] + f5[i*5+1]*xm[3][i] + f5[i*5+2]*xm[2][i]
              + f5[i*5+3]*xm[1][i] + f5[i*5+4]*xm[0][i];
    }

#pragma unroll
    for (int i = 0; i < 8; ++i) { u0[i] = xm[0][i] - t3[i]; u1[i] = xm[0][i] - t5[i]; }
    route2(u0, u1, vv);
    {
        u16x8 pk;
#pragma unroll
        for (int i = 0; i < 8; ++i) pk[i] = f2bf(vv[i]);
        *(u16x8*)(vs + (size_t)p*DCH + c0) = pk;
    }
    route2(t3, t5, vv);
    {
        u16x8 pk;
#pragma unroll
        for (int i = 0; i < 8; ++i) pk[i] = f2bf(vv[i]);
        *(u16x8*)(vt + (size_t)p*DCH + c0) = pk;
    }
}

// ---------------------------------------------------------------------------
// Kernel 1b: coalesced transpose [n][l][c] -> [n][c][l], 64x64 LDS tiles.
// grid (8 ctiles, 32 ltiles, 16 = tensor*8+n), 256 threads.
// ---------------------------------------------------------------------------
__global__ __launch_bounds__(256) void transpose_cm(
    const u16* __restrict__ vs, const u16* __restrict__ vt,
    u16* __restrict__ vsT, u16* __restrict__ vtT)
{
    __shared__ u16 T[64][65];
    const int z = blockIdx.z;
    const u16* src = ((z & 8) ? vt : vs) + (size_t)(z & 7) * LSEQ * DCH;
    u16*       dst = ((z & 8) ? vtT : vsT) + (size_t)(z & 7) * DCH * LSEQ;
    const int l0 = blockIdx.y * 64, c0 = blockIdx.x * 64;
    const int tid = threadIdx.x;
    const int rl = tid >> 3, cc = (tid & 7) * 8;
#pragma unroll
    for (int i = 0; i < 2; ++i) {
        int row = rl + i*32;
        *(u16x8*)(&T[row][cc]) = *(const u16x8*)(src + (size_t)(l0+row)*DCH + c0 + cc);
    }
    __syncthreads();
    const int ch = tid >> 3, lc = (tid & 7) * 8;
#pragma unroll
    for (int i = 0; i < 2; ++i) {
        int c = ch + i*32;
        u16x8 o;
#pragma unroll
        for (int j = 0; j < 8; ++j) o[j] = T[lc + j][c];
        *(u16x8*)(dst + (size_t)(c0 + c)*LSEQ + l0 + lc) = o;
    }
}

// ---------------------------------------------------------------------------
// Kernel 2: windowed causal attention with exp(-decay*dist) bias.
// grid (32 row-blocks, 16 instances), 256 threads (4 independent waves).
// Wave w owns query rows r0+16w..+15; 8 key-tiles of 32 (window).
// Barrier-free: K from row-major global, V from transposed global, P via
// per-wave LDS round-trip only.
// ---------------------------------------------------------------------------
__global__ __launch_bounds__(256) void attn(
    const u16* __restrict__ vs, const u16* __restrict__ vt,
    const u16* __restrict__ vsT, const u16* __restrict__ vtT,
    u16* __restrict__ cat)
{
    __shared__ u16 Ps[4][16][40];  // per-wave P [local row][key], stride 80B

    const int inst = blockIdx.y;
    const int t = inst >> 3, n = inst & 7;
    const u16* src  = (t ? vt  : vs)  + (size_t)n * LSEQ * DCH;
    const u16* srcT = (t ? vtT : vsT) + (size_t)n * DCH * LSEQ;

    const int r0  = blockIdx.x * 64;
    const int tid  = threadIdx.x;
    const int wid  = tid >> 6, lane = tid & 63;
    const int l16  = lane & 15, quad = lane >> 4;

    // Q A-frags register-resident
    bf16x8 qf[16];
    {
        const u16* qp = src + (size_t)(r0 + wid*16 + l16) * DCH + quad*8;
#pragma unroll
        for (int kc = 0; kc < 16; ++kc) qf[kc] = *(const bf16x8*)(qp + kc*32);
    }

    f32x4 O[32];
#pragma unroll
    for (int i = 0; i < 32; ++i) O[i] = (f32x4){0.f, 0.f, 0.f, 0.f};
    float m_old[4] = {-__builtin_inff(), -__builtin_inff(), -__builtin_inff(), -__builtin_inff()};
    float l_run[4] = {0.f, 0.f, 0.f, 0.f};

    const int kb_hi = (r0 >> 5) + 1;                       // diagonal tile (incl)
    const int kb_lo = (kb_hi >= WTILES) ? kb_hi - (WTILES-1) : 0;
    for (int kb = kb_lo; kb <= kb_hi; ++kb) {
        // Phase A: S[16x32] = Q * K^T ; B-frags from row-major global (L1/L2)
        f32x4 S0 = {0.f,0.f,0.f,0.f}, S1 = {0.f,0.f,0.f,0.f};
        {
            const u16* kB = src + (size_t)(kb*32 + l16) * DCH + quad*8;
#pragma unroll
            for (int kc = 0; kc < 16; ++kc) {
                bf16x8 b0 = *(const bf16x8*)(kB + kc*32);
                bf16x8 b1 = *(const bf16x8*)(kB + 16*DCH + kc*32);
                S0 = __builtin_amdgcn_mfma_f32_16x16x32_bf16(qf[kc], b0, S0, 0, 0, 0);
                S1 = __builtin_amdgcn_mfma_f32_16x16x32_bf16(qf[kc], b1, S1, 0, 0, 0);
            }
        }

        // online softmax (C-layout: row = quad*4+r, key = l16 within tile)
        float al[4];
        const int rowg = r0 + wid*16 + quad*4;
#pragma unroll
        for (int r = 0; r < 4; ++r) {
            int row = rowg + r;
            int d0  = row - (kb*32 + l16);
            int d1  = d0 - 16;
            float s0 = (d0 >= 0) ? (S0[r] - DECAYF * (float)d0) : -__builtin_inff();
            float s1 = (d1 >= 0) ? (S1[r] - DECAYF * (float)d1) : -__builtin_inff();
            float rm = fmaxf(s0, s1);
            rm = fmaxf(rm, __shfl_xor(rm, 1, 64));
            rm = fmaxf(rm, __shfl_xor(rm, 2, 64));
            rm = fmaxf(rm, __shfl_xor(rm, 4, 64));
            rm = fmaxf(rm, __shfl_xor(rm, 8, 64));
            float mn = fmaxf(m_old[r], rm);
            float a  = __expf(m_old[r] - mn);
            m_old[r] = mn;
            float p0 = __expf(s0 - mn);
            float p1 = __expf(s1 - mn);
            Ps[wid][quad*4 + r][l16]      = f2bf(p0);
            Ps[wid][quad*4 + r][16 + l16] = f2bf(p1);
            float rs = p0 + p1;
            rs += __shfl_xor(rs, 1, 64);
            rs += __shfl_xor(rs, 2, 64);
            rs += __shfl_xor(rs, 4, 64);
            rs += __shfl_xor(rs, 8, 64);
            l_run[r] = l_run[r] * a + rs;
            al[r] = a;
        }
#pragma unroll
        for (int ct = 0; ct < 32; ++ct) {
            O[ct][0] *= al[0]; O[ct][1] *= al[1]; O[ct][2] *= al[2]; O[ct][3] *= al[3];
        }

        // Phase B: O[16x512] += P[16x32] * V[32x512]; V B-frags from global vT
        bf16x8 pf = *(const bf16x8*)(&Ps[wid][l16][quad*8]);   // wave-coherent LDS
        const u16* vB = srcT + (size_t)l16 * LSEQ + kb*32 + quad*8;
#pragma unroll
        for (int ct = 0; ct < 32; ++ct) {
            bf16x8 vf = *(const bf16x8*)(vB + (size_t)ct*16*LSEQ);
            O[ct] = __builtin_amdgcn_mfma_f32_16x16x32_bf16(pf, vf, O[ct], 0, 0, 0);
        }
    }

    // epilogue: O /= l, write bf16 into cat
    float inv[4];
#pragma unroll
    for (int r = 0; r < 4; ++r) inv[r] = 1.f / l_run[r];
    const size_t rowbase = (size_t)n * LSEQ + r0 + wid*16 + quad*4;
    const int colbase = t * 512 + l16;
#pragma unroll
    for (int ct = 0; ct < 32; ++ct) {
#pragma unroll
        for (int r = 0; r < 4; ++r)
            cat[(rowbase + r) * 1024 + colbase + ct*16] = f2bf(O[ct][r] * inv[r]);
    }
}

// ---------------------------------------------------------------------------
// Kernel 3: cast fusion_w fp32 -> bf16
// ---------------------------------------------------------------------------
__global__ __launch_bounds__(256) void cast_w(const float* __restrict__ w, u16* __restrict__ wb)
{
    int id = blockIdx.x * 256 + threadIdx.x;   // 131072 float4 chunks
    float4 f = ((const float4*)w)[id];
    u16x4 o;
    o[0] = f2bf(f.x); o[1] = f2bf(f.y); o[2] = f2bf(f.z); o[3] = f2bf(f.w);
    ((u16x4*)wb)[id] = o;
}

// ---------------------------------------------------------------------------
// Kernel 4: out[16384,512] = cat[16384,1024] @ W[512,1024]^T + bias (fp32 out)
// ---------------------------------------------------------------------------
__global__ __launch_bounds__(256) void fusion_gemm(
    const u16* __restrict__ A, const u16* __restrict__ B,
    const float* __restrict__ bias, float* __restrict__ out)
{
    __shared__ u16 As[128][72];
    __shared__ u16 Bs[128][72];
    const int m0 = blockIdx.x * 128;
    const int n0 = blockIdx.y * 128;
    const int tid = threadIdx.x;
    const int wid = tid >> 6, lane = tid & 63;
    const int l16 = lane & 15, quad = lane >> 4;
    const int wm = (wid >> 1) * 64, wn = (wid & 1) * 64;

    f32x4 acc[4][4];
#pragma unroll
    for (int i = 0; i < 4; ++i)
#pragma unroll
        for (int j = 0; j < 4; ++j) acc[i][j] = (f32x4){0.f, 0.f, 0.f, 0.f};

    for (int kb = 0; kb < 16; ++kb) {
#pragma unroll
        for (int i = 0; i < 4; ++i) {
            int id = tid + i*256;
            int row = id >> 3, kc = id & 7;
            *(u16x8*)(&As[row][kc*8]) = *(const u16x8*)(A + (size_t)(m0+row)*1024 + kb*64 + kc*8);
            *(u16x8*)(&Bs[row][kc*8]) = *(const u16x8*)(B + (size_t)(n0+row)*1024 + kb*64 + kc*8);
        }
        __syncthreads();
#pragma unroll
        for (int k2 = 0; k2 < 2; ++k2) {
            bf16x8 af[4], bfr[4];
#pragma unroll
            for (int i = 0; i < 4; ++i) {
                af[i]  = *(const bf16x8*)(&As[wm + i*16 + l16][k2*32 + quad*8]);
                bfr[i] = *(const bf16x8*)(&Bs[wn + i*16 + l16][k2*32 + quad*8]);
            }
#pragma unroll
            for (int i = 0; i < 4; ++i)
#pragma unroll
                for (int j = 0; j < 4; ++j)
                    acc[i][j] = __builtin_amdgcn_mfma_f32_16x16x32_bf16(af[i], bfr[j], acc[i][j], 0, 0, 0);
        }
        __syncthreads();
    }
#pragma unroll
    for (int j = 0; j < 4; ++j) {
        int col = n0 + wn + j*16 + l16;
        float bv = bias[col];
#pragma unroll
        for (int i = 0; i < 4; ++i) {
            int rowb = m0 + wm + i*16 + quad*4;
#pragma unroll
            for (int r = 0; r < 4; ++r)
                out[(size_t)(rowb + r)*512 + col] = acc[i][j][r] + bv;
        }
    }
}

// ---------------------------------------------------------------------------
extern "C" void kernel_launch(void* const* d_in, const int* in_sizes, int n_in,
                              void* d_out, int out_size, void* d_ws, size_t ws_size,
                              hipStream_t stream)
{
    (void)in_sizes; (void)n_in; (void)out_size; (void)ws_size;
    const float* x  = (const float*)d_in[0];
    const float* w3 = (const float*)d_in[1];
    const float* w5 = (const float*)d_in[2];
    const float* fw = (const float*)d_in[3];
    const float* fb = (const float*)d_in[4];
    float* out = (float*)d_out;

    const size_t SZ = (size_t)NBATCH * LSEQ * DCH;   // 8.39M elements
    u16* vs  = (u16*)d_ws;      // [N,L,D] bf16
    u16* vt  = vs  + SZ;
    u16* vsT = vt  + SZ;        // [N,D,L] bf16
    u16* vtT = vsT + SZ;
    u16* cat = vtT + SZ;        // [N*L, 1024] bf16
    u16* wb  = cat + 2*SZ;      // [512,1024] bf16

    cast_w      <<<512, 256, 0, stream>>>(fw, wb);
    conv_route  <<<4096, 256, 0, stream>>>(x, w3, w5, vs, vt);
    transpose_cm<<<dim3(8, 32, 16), 256, 0, stream>>>(vs, vt, vsT, vtT);
    attn        <<<dim3(32, 16), 256, 0, stream>>>(vs, vt, vsT, vtT, cat);
    fusion_gemm <<<dim3(128, 4), 256, 0, stream>>>(cat, wb, fb, out);
}

// Round 3
// 228.013 us; speedup vs baseline: 4.5553x; 1.6718x over previous
//
#include <hip/hip_runtime.h>

// ---------------------------------------------------------------------------
// capsule_87840671138361: conv->routing->attention->fusion, MI355X (gfx950)
// R3 changes vs R2 (attn was latency-serial: MLP~1, 600cyc/load):
//  - attn: K/V tiles staged to LDS via global_load_lds width=16 (async DMA,
//    no VGPR cost, 65 loads in flight) -> per-block single fetch of each tile
//    (was per-wave), frags via ds_read_b128.
//  - v stored with PADDED global row stride (520 ch = 1040B) so the LDS
//    mirror gets a 4-bank row shift (2-way conflicts = free) without LDS pads.
//  - V stored pre-tiled [kb][512ch][32key] (32KB contiguous) for DMA.
//  - XCD-aware strip swizzle for window-overlap L2 locality.
// ---------------------------------------------------------------------------

typedef short     bf16x8 __attribute__((ext_vector_type(8)));  // MFMA A/B frag
typedef float     f32x4  __attribute__((ext_vector_type(4)));  // MFMA C/D frag
typedef unsigned short u16;
typedef u16       u16x8  __attribute__((ext_vector_type(8)));
typedef u16       u16x4  __attribute__((ext_vector_type(4)));

#define NBATCH 8
#define LSEQ   2048
#define DCH    512
#define DPAD   520      // padded row stride (elems): 1040B = 65x16B, 4-bank row shift
#define DECAYF 0.2f
#define WTILES 8        // window = 8 key-tiles of 32 (decay kills the rest: <1e-15)

typedef const __attribute__((address_space(1))) unsigned char* gas_t;
typedef __attribute__((address_space(3))) unsigned char* las_t;
__device__ __forceinline__ void dma16(const void* g, void* l) {
    __builtin_amdgcn_global_load_lds((gas_t)g, (las_t)l, 16, 0, 0);
}

__device__ __forceinline__ u16 f2bf(float f) {
    unsigned int u = __float_as_uint(f);
    u += 0x7fffu + ((u >> 16) & 1u);   // RNE; inputs never NaN
    return (u16)(u >> 16);
}

__device__ __forceinline__ float wave_sum(float v) {
#pragma unroll
    for (int m = 1; m < 64; m <<= 1) v += __shfl_xor(v, m, 64);
    return v;
}

// ---------------------------------------------------------------------------
// Kernel 1: fused causal depthwise conv (k=3,5) + dynamic routing (3 iters)
// One wave per (n,l). Writes v rows with DPAD stride.
// ---------------------------------------------------------------------------
__device__ __forceinline__ void route2(const float* u0, const float* u1, float* vout) {
    float b0 = 0.f, b1 = 0.f;
#pragma unroll
    for (int it = 0; it < 3; ++it) {
        float mx  = fmaxf(b0, b1);
        float e0  = __expf(b0 - mx), e1 = __expf(b1 - mx);
        float inv = 1.f / (e0 + e1);
        float c0 = e0 * inv, c1 = e1 * inv;
        float n2 = 0.f;
        float s[8];
#pragma unroll
        for (int i = 0; i < 8; ++i) { s[i] = c0*u0[i] + c1*u1[i]; n2 += s[i]*s[i]; }
        n2 = wave_sum(n2);
        float nrm = sqrtf(n2);
        float sc  = n2 / ((1.f + n2) * (nrm + 1e-9f));   // squash scale
#pragma unroll
        for (int i = 0; i < 8; ++i) vout[i] = sc * s[i];
        if (it < 2) {
            float d0 = 0.f, d1 = 0.f;
#pragma unroll
            for (int i = 0; i < 8; ++i) { d0 += u0[i]*vout[i]; d1 += u1[i]*vout[i]; }
            d0 = wave_sum(d0); d1 = wave_sum(d1);
            b0 += d0; b1 += d1;
        }
    }
}

__global__ __launch_bounds__(256) void conv_route(
    const float* __restrict__ x, const float* __restrict__ w3, const float* __restrict__ w5,
    u16* __restrict__ vs, u16* __restrict__ vt)
{
    const int wid  = threadIdx.x >> 6;
    const int lane = threadIdx.x & 63;
    const int p = blockIdx.x * 4 + wid;          // 16384 positions
    const int n = p >> 11, l = p & (LSEQ - 1);
    const int c0 = lane * 8;

    float xm[5][8];
#pragma unroll
    for (int j = 0; j < 5; ++j) {
        int ll = l - j;
        if (ll >= 0) {
            const float4* sp = (const float4*)(x + ((size_t)(n*LSEQ + ll))*DCH + c0);
            float4 a = sp[0], b = sp[1];
            xm[j][0]=a.x; xm[j][1]=a.y; xm[j][2]=a.z; xm[j][3]=a.w;
            xm[j][4]=b.x; xm[j][5]=b.y; xm[j][6]=b.z; xm[j][7]=b.w;
        } else {
#pragma unroll
            for (int i = 0; i < 8; ++i) xm[j][i] = 0.f;
        }
    }
    float f3[24], f5[40];
#pragma unroll
    for (int k = 0; k < 6; ++k)  ((float4*)f3)[k] = ((const float4*)(w3 + (size_t)c0*3))[k];
#pragma unroll
    for (int k = 0; k < 10; ++k) ((float4*)f5)[k] = ((const float4*)(w5 + (size_t)c0*5))[k];

    float t3[8], t5[8], u0[8], u1[8], vv[8];
#pragma unroll
    for (int i = 0; i < 8; ++i) {
        t3[i] = f3[i*3+0]*xm[2][i] + f3[i*3+1]*xm[1][i] + f3[i*3+2]*xm[0][i];
        t5[i] = f5[i*5+0]*xm[4][i] + f5[i*5+1]*xm[3][i] + f5[i*5+2]*xm[2][i]
              + f5[i*5+3]*xm[1][i] + f5[i*5+4]*xm[0][i];
    }

#pragma unroll
    for (int i = 0; i < 8; ++i) { u0[i] = xm[0][i] - t3[i]; u1[i] = xm[0][i] - t5[i]; }
    route2(u0, u1, vv);
    {
        u16x8 pk;
#pragma unroll
        for (int i = 0; i < 8; ++i) pk[i] = f2bf(vv[i]);
        *(u16x8*)(vs + (size_t)p*DPAD + c0) = pk;
    }
    route2(t3, t5, vv);
    {
        u16x8 pk;
#pragma unroll
        for (int i = 0; i < 8; ++i) pk[i] = f2bf(vv[i]);
        *(u16x8*)(vt + (size_t)p*DPAD + c0) = pk;
    }
}

// ---------------------------------------------------------------------------
// Kernel 1b: transpose padded rows [n][l][520] -> V tiles [n][kb][512ch][32key]
// 64x64 LDS tiles. grid (8 ctiles, 32 ltiles, 16 = tensor*8+n), 256 threads.
// ---------------------------------------------------------------------------
__global__ __launch_bounds__(256) void transpose_vtile(
    const u16* __restrict__ vs, const u16* __restrict__ vt,
    u16* __restrict__ vsTt, u16* __restrict__ vtTt)
{
    __shared__ u16 T[64][65];
    const int z = blockIdx.z;
    const u16* src = ((z & 8) ? vt : vs) + (size_t)(z & 7) * LSEQ * DPAD;
    u16*       dst = ((z & 8) ? vtTt : vsTt) + (size_t)(z & 7) * 64 * DCH * 32;
    const int l0 = blockIdx.y * 64, c0 = blockIdx.x * 64;
    const int tid = threadIdx.x;
    const int rl = tid >> 3, cc = (tid & 7) * 8;
#pragma unroll
    for (int i = 0; i < 2; ++i) {
        int row = rl + i*32;
        *(u16x8*)(&T[row][cc]) = *(const u16x8*)(src + (size_t)(l0+row)*DPAD + c0 + cc);
    }
    __syncthreads();
    const int ch = tid >> 3, lc = (tid & 7) * 8;   // lc in {0,8,...,56}
#pragma unroll
    for (int i = 0; i < 2; ++i) {
        int c = ch + i*32;
        u16x8 o;
#pragma unroll
        for (int j = 0; j < 8; ++j) o[j] = T[lc + j][c];
        // tile index (l0+lc)>>5 ; key-in-tile lc&31 (stays within one tile for j<8)
        *(u16x8*)(dst + (size_t)((l0 + lc) >> 5) * (DCH*32)
                      + (size_t)(c0 + c) * 32 + (lc & 31)) = o;
    }
}

// ---------------------------------------------------------------------------
// Kernel 2: windowed causal attention, LDS-staged K/V via global_load_lds.
// grid (32 strips, 16 instances), 256 threads (4 waves). 64 q-rows/block.
// K tile: LDS mirror of 32 padded rows (33.25KB + 0.5KB DMA slack).
// V tile: LDS copy of pre-tiled [512][32] (32KB).
// ---------------------------------------------------------------------------
__global__ __launch_bounds__(256) void attn(
    const u16* __restrict__ vs, const u16* __restrict__ vt,
    const u16* __restrict__ vsTt, const u16* __restrict__ vtTt,
    u16* __restrict__ cat)
{
    __shared__ u16 Ks[33792/2];    // 33 KB: 32 rows x 1040B + 512B slack
    __shared__ u16 Vs[DCH*32];     // 32 KB
    __shared__ u16 Ps[4][16][40];  // per-wave P, stride 80B

    const int inst = blockIdx.y;
    const int t = inst >> 3, n = inst & 7;
    const u16* src  = (t ? vt : vs) + (size_t)n * LSEQ * DPAD;
    const u16* srcT = (t ? vtTt : vsTt) + (size_t)n * 64 * DCH * 32;

    // XCD swizzle: strips {4k..4k+3} share XCD k (lin%8 = blockIdx.x%8)
    const int bx = blockIdx.x;
    const int r0 = (((bx & 7) << 2) | (bx >> 3)) * 64;

    const int tid  = threadIdx.x;
    const int wid  = tid >> 6, lane = tid & 63;
    const int l16  = lane & 15, quad = lane >> 4;

    // Q A-frags register-resident (from padded rows)
    bf16x8 qf[16];
    {
        const u16* qp = src + (size_t)(r0 + wid*16 + l16) * DPAD + quad*8;
#pragma unroll
        for (int kc = 0; kc < 16; ++kc) qf[kc] = *(const bf16x8*)(qp + kc*32);
    }

    f32x4 O[32];
#pragma unroll
    for (int i = 0; i < 32; ++i) O[i] = (f32x4){0.f, 0.f, 0.f, 0.f};
    float m_old[4] = {-__builtin_inff(), -__builtin_inff(), -__builtin_inff(), -__builtin_inff()};
    float l_run[4] = {0.f, 0.f, 0.f, 0.f};

    const int kb_hi = (r0 >> 5) + 1;
    const int kb_lo = (kb_hi >= WTILES) ? kb_hi - (WTILES-1) : 0;
    for (int kb = kb_lo; kb <= kb_hi; ++kb) {
        __syncthreads();   // all waves done reading previous tiles
        // async DMA: K tile = 33 x 1KB (contiguous padded rows), V tile = 32 x 1KB
        {
            const u16* gK = src + (size_t)kb * 32 * DPAD;
            for (int i = wid; i < 33; i += 4)
                dma16(gK + i*512 + lane*8, Ks + i*512);
            const u16* gV = srcT + (size_t)kb * (DCH*32);
            for (int i = wid; i < 32; i += 4)
                dma16(gV + i*512 + lane*8, Vs + i*512);
        }
        __syncthreads();   // compiler drains vmcnt before barrier -> tiles ready

        // Phase A: S[16x32] = Q * K^T ; B-frags from LDS K mirror
        f32x4 S0 = {0.f,0.f,0.f,0.f}, S1 = {0.f,0.f,0.f,0.f};
#pragma unroll
        for (int kc = 0; kc < 16; ++kc) {
            bf16x8 b0 = *(const bf16x8*)(Ks + (size_t)l16*DPAD + kc*32 + quad*8);
            bf16x8 b1 = *(const bf16x8*)(Ks + (size_t)(16+l16)*DPAD + kc*32 + quad*8);
            S0 = __builtin_amdgcn_mfma_f32_16x16x32_bf16(qf[kc], b0, S0, 0, 0, 0);
            S1 = __builtin_amdgcn_mfma_f32_16x16x32_bf16(qf[kc], b1, S1, 0, 0, 0);
        }

        // online softmax (C-layout: row = quad*4+r, key = l16 within tile)
        float al[4];
        const int rowg = r0 + wid*16 + quad*4;
#pragma unroll
        for (int r = 0; r < 4; ++r) {
            int row = rowg + r;
            int d0  = row - (kb*32 + l16);
            int d1  = d0 - 16;
            float s0 = (d0 >= 0) ? (S0[r] - DECAYF * (float)d0) : -__builtin_inff();
            float s1 = (d1 >= 0) ? (S1[r] - DECAYF * (float)d1) : -__builtin_inff();
            float rm = fmaxf(s0, s1);
            rm = fmaxf(rm, __shfl_xor(rm, 1, 64));
            rm = fmaxf(rm, __shfl_xor(rm, 2, 64));
            rm = fmaxf(rm, __shfl_xor(rm, 4, 64));
            rm = fmaxf(rm, __shfl_xor(rm, 8, 64));
            float mn = fmaxf(m_old[r], rm);
            float a  = __expf(m_old[r] - mn);
            m_old[r] = mn;
            float p0 = __expf(s0 - mn);
            float p1 = __expf(s1 - mn);
            Ps[wid][quad*4 + r][l16]      = f2bf(p0);
            Ps[wid][quad*4 + r][16 + l16] = f2bf(p1);
            float rs = p0 + p1;
            rs += __shfl_xor(rs, 1, 64);
            rs += __shfl_xor(rs, 2, 64);
            rs += __shfl_xor(rs, 4, 64);
            rs += __shfl_xor(rs, 8, 64);
            l_run[r] = l_run[r] * a + rs;
            al[r] = a;
        }
#pragma unroll
        for (int ct = 0; ct < 32; ++ct) {
            O[ct][0] *= al[0]; O[ct][1] *= al[1]; O[ct][2] *= al[2]; O[ct][3] *= al[3];
        }

        // Phase B: O[16x512] += P[16x32] * V[32x512]; V B-frags from LDS tile
        bf16x8 pf = *(const bf16x8*)(&Ps[wid][l16][quad*8]);   // wave-local
#pragma unroll
        for (int ct = 0; ct < 32; ++ct) {
            bf16x8 vf = *(const bf16x8*)(Vs + (size_t)(ct*16 + l16)*32 + quad*8);
            O[ct] = __builtin_amdgcn_mfma_f32_16x16x32_bf16(pf, vf, O[ct], 0, 0, 0);
        }
    }

    // epilogue
    float inv[4];
#pragma unroll
    for (int r = 0; r < 4; ++r) inv[r] = 1.f / l_run[r];
    const size_t rowbase = (size_t)n * LSEQ + r0 + wid*16 + quad*4;
    const int colbase = t * 512 + l16;
#pragma unroll
    for (int ct = 0; ct < 32; ++ct) {
#pragma unroll
        for (int r = 0; r < 4; ++r)
            cat[(rowbase + r) * 1024 + colbase + ct*16] = f2bf(O[ct][r] * inv[r]);
    }
}

// ---------------------------------------------------------------------------
// Kernel 3: cast fusion_w fp32 -> bf16
// ---------------------------------------------------------------------------
__global__ __launch_bounds__(256) void cast_w(const float* __restrict__ w, u16* __restrict__ wb)
{
    int id = blockIdx.x * 256 + threadIdx.x;
    float4 f = ((const float4*)w)[id];
    u16x4 o;
    o[0] = f2bf(f.x); o[1] = f2bf(f.y); o[2] = f2bf(f.z); o[3] = f2bf(f.w);
    ((u16x4*)wb)[id] = o;
}

// ---------------------------------------------------------------------------
// Kernel 4: out[16384,512] = cat[16384,1024] @ W[512,1024]^T + bias (fp32 out)
// ---------------------------------------------------------------------------
__global__ __launch_bounds__(256) void fusion_gemm(
    const u16* __restrict__ A, const u16* __restrict__ B,
    const float* __restrict__ bias, float* __restrict__ out)
{
    __shared__ u16 As[128][72];
    __shared__ u16 Bs[128][72];
    const int m0 = blockIdx.x * 128;
    const int n0 = blockIdx.y * 128;
    const int tid = threadIdx.x;
    const int wid = tid >> 6, lane = tid & 63;
    const int l16 = lane & 15, quad = lane >> 4;
    const int wm = (wid >> 1) * 64, wn = (wid & 1) * 64;

    f32x4 acc[4][4];
#pragma unroll
    for (int i = 0; i < 4; ++i)
#pragma unroll
        for (int j = 0; j < 4; ++j) acc[i][j] = (f32x4){0.f, 0.f, 0.f, 0.f};

    for (int kb = 0; kb < 16; ++kb) {
#pragma unroll
        for (int i = 0; i < 4; ++i) {
            int id = tid + i*256;
            int row = id >> 3, kc = id & 7;
            *(u16x8*)(&As[row][kc*8]) = *(const u16x8*)(A + (size_t)(m0+row)*1024 + kb*64 + kc*8);
            *(u16x8*)(&Bs[row][kc*8]) = *(const u16x8*)(B + (size_t)(n0+row)*1024 + kb*64 + kc*8);
        }
        __syncthreads();
#pragma unroll
        for (int k2 = 0; k2 < 2; ++k2) {
            bf16x8 af[4], bfr[4];
#pragma unroll
            for (int i = 0; i < 4; ++i) {
                af[i]  = *(const bf16x8*)(&As[wm + i*16 + l16][k2*32 + quad*8]);
                bfr[i] = *(const bf16x8*)(&Bs[wn + i*16 + l16][k2*32 + quad*8]);
            }
#pragma unroll
            for (int i = 0; i < 4; ++i)
#pragma unroll
                for (int j = 0; j < 4; ++j)
                    acc[i][j] = __builtin_amdgcn_mfma_f32_16x16x32_bf16(af[i], bfr[j], acc[i][j], 0, 0, 0);
        }
        __syncthreads();
    }
#pragma unroll
    for (int j = 0; j < 4; ++j) {
        int col = n0 + wn + j*16 + l16;
        float bv = bias[col];
#pragma unroll
        for (int i = 0; i < 4; ++i) {
            int rowb = m0 + wm + i*16 + quad*4;
#pragma unroll
            for (int r = 0; r < 4; ++r)
                out[(size_t)(rowb + r)*512 + col] = acc[i][j][r] + bv;
        }
    }
}

// ---------------------------------------------------------------------------
extern "C" void kernel_launch(void* const* d_in, const int* in_sizes, int n_in,
                              void* d_out, int out_size, void* d_ws, size_t ws_size,
                              hipStream_t stream)
{
    (void)in_sizes; (void)n_in; (void)out_size; (void)ws_size;
    const float* x  = (const float*)d_in[0];
    const float* w3 = (const float*)d_in[1];
    const float* w5 = (const float*)d_in[2];
    const float* fw = (const float*)d_in[3];
    const float* fb = (const float*)d_in[4];
    float* out = (float*)d_out;

    const size_t SZP = (size_t)NBATCH * LSEQ * DPAD;    // 8.52M (padded rows)
    const size_t SZT = (size_t)NBATCH * 64 * DCH * 32;  // 8.39M (V tiles)
    u16* vs   = (u16*)d_ws;        // [N][L][520]
    u16* vt   = vs   + SZP;
    u16* vsTt = vt   + SZP;        // [N][64][512][32]
    u16* vtTt = vsTt + SZT;
    u16* cat  = vtTt + SZT;        // [N*L][1024]
    u16* wb   = cat  + (size_t)NBATCH*LSEQ*1024;   // [512][1024]
    // total ~102 MB (DMA tail slack reads spill into the next region: benign)

    cast_w        <<<512, 256, 0, stream>>>(fw, wb);
    conv_route    <<<4096, 256, 0, stream>>>(x, w3, w5, vs, vt);
    transpose_vtile<<<dim3(8, 32, 16), 256, 0, stream>>>(vs, vt, vsTt, vtTt);
    attn          <<<dim3(32, 16), 256, 0, stream>>>(vs, vt, vsTt, vtTt, cat);
    fusion_gemm   <<<dim3(128, 4), 256, 0, stream>>>(cat, wb, fb, out);
}

// Round 4
// 200.157 us; speedup vs baseline: 5.1892x; 1.1392x over previous
//
#include <hip/hip_runtime.h>

// ---------------------------------------------------------------------------
// capsule_87840671138361: conv->routing->attention->fusion, MI355X (gfx950)
// R4 changes vs R3:
//  - attn: FIXED-max softmax (m=1; valid since |sim|<1 for squashed vectors &
//    self-score>=0) -> no shuffle reductions, no alpha rescale of O.
//  - attn: row-sum l via ones-B-frag MFMA (register constant, no LDS).
//  - attn: W=6 key-tiles (128-key min window; truncated mass ~1e-10).
//  - attn: DMA overlapped with compute (V(kb) overlaps Phase A, K(kb+1)
//    overlaps Phase B); still 2 barriers/iter but drains are hidden.
//  - keys stored INTERLEAVED (slot=2*(k&15)+(k>>4)) in V tiles & Ps so P is
//    written as one packed u32 per row.
//  - cast_w folded into fusion_gemm staging (w read fp32, cvt in-flight).
//  - conv_route: both routings' shuffle chains interleaved (2x ILP).
// ---------------------------------------------------------------------------

typedef short     bf16x8 __attribute__((ext_vector_type(8)));  // MFMA A/B frag
typedef float     f32x4  __attribute__((ext_vector_type(4)));  // MFMA C/D frag
typedef unsigned short u16;
typedef u16       u16x8  __attribute__((ext_vector_type(8)));

#define NBATCH 8
#define LSEQ   2048
#define DCH    512
#define DPAD   520      // padded row stride (elems): 1040B, 4-bank row shift
#define DECAYF 0.2f
#define WTILES 6        // 128-key min window; tail mass ~1e-10 << fp32 eps

typedef const __attribute__((address_space(1))) unsigned char* gas_t;
typedef __attribute__((address_space(3))) unsigned char* las_t;
__device__ __forceinline__ void dma16(const void* g, void* l) {
    __builtin_amdgcn_global_load_lds((gas_t)g, (las_t)l, 16, 0, 0);
}

__device__ __forceinline__ u16 f2bf(float f) {
    unsigned int u = __float_as_uint(f);
    u += 0x7fffu + ((u >> 16) & 1u);   // RNE; inputs never NaN
    return (u16)(u >> 16);
}

// ---------------------------------------------------------------------------
// Kernel 1: fused causal depthwise conv (k=3,5) + 2x dynamic routing, with
// the two routings' reduction chains interleaved for ILP.
// ---------------------------------------------------------------------------
__device__ __forceinline__ void wave_sum2(float& a, float& b) {
#pragma unroll
    for (int m = 1; m < 64; m <<= 1) {
        float ta = __shfl_xor(a, m, 64);
        float tb = __shfl_xor(b, m, 64);
        a += ta; b += tb;
    }
}
__device__ __forceinline__ void wave_sum4(float& a, float& b, float& c, float& d) {
#pragma unroll
    for (int m = 1; m < 64; m <<= 1) {
        float ta = __shfl_xor(a, m, 64);
        float tb = __shfl_xor(b, m, 64);
        float tc = __shfl_xor(c, m, 64);
        float td = __shfl_xor(d, m, 64);
        a += ta; b += tb; c += tc; d += td;
    }
}

__global__ __launch_bounds__(256) void conv_route(
    const float* __restrict__ x, const float* __restrict__ w3, const float* __restrict__ w5,
    u16* __restrict__ vs, u16* __restrict__ vt)
{
    const int wid  = threadIdx.x >> 6;
    const int lane = threadIdx.x & 63;
    const int p = blockIdx.x * 4 + wid;          // 16384 positions
    const int n = p >> 11, l = p & (LSEQ - 1);
    const int c0 = lane * 8;

    float xm[5][8];
#pragma unroll
    for (int j = 0; j < 5; ++j) {
        int ll = l - j;
        if (ll >= 0) {
            const float4* sp = (const float4*)(x + ((size_t)(n*LSEQ + ll))*DCH + c0);
            float4 a = sp[0], b = sp[1];
            xm[j][0]=a.x; xm[j][1]=a.y; xm[j][2]=a.z; xm[j][3]=a.w;
            xm[j][4]=b.x; xm[j][5]=b.y; xm[j][6]=b.z; xm[j][7]=b.w;
        } else {
#pragma unroll
            for (int i = 0; i < 8; ++i) xm[j][i] = 0.f;
        }
    }
    float f3[24], f5[40];
#pragma unroll
    for (int k = 0; k < 6; ++k)  ((float4*)f3)[k] = ((const float4*)(w3 + (size_t)c0*3))[k];
#pragma unroll
    for (int k = 0; k < 10; ++k) ((float4*)f5)[k] = ((const float4*)(w5 + (size_t)c0*5))[k];

    float t3[8], t5[8], a0[8], a1[8];
#pragma unroll
    for (int i = 0; i < 8; ++i) {
        t3[i] = f3[i*3+0]*xm[2][i] + f3[i*3+1]*xm[1][i] + f3[i*3+2]*xm[0][i];
        t5[i] = f5[i*5+0]*xm[4][i] + f5[i*5+1]*xm[3][i] + f5[i*5+2]*xm[2][i]
              + f5[i*5+3]*xm[1][i] + f5[i*5+4]*xm[0][i];
        a0[i] = xm[0][i] - t3[i];
        a1[i] = xm[0][i] - t5[i];
    }

    // two routings (seasonal: a0,a1 ; trend: t3,t5) interleaved
    float ba0=0.f, ba1=0.f, bb0=0.f, bb1=0.f;
    float va[8], vb[8];
#pragma unroll
    for (int it = 0; it < 3; ++it) {
        float mxa = fmaxf(ba0, ba1), mxb = fmaxf(bb0, bb1);
        float ea0 = __expf(ba0-mxa), ea1 = __expf(ba1-mxa);
        float eb0 = __expf(bb0-mxb), eb1 = __expf(bb1-mxb);
        float ia = 1.f/(ea0+ea1), ib = 1.f/(eb0+eb1);
        float ca0 = ea0*ia, ca1 = ea1*ia, cb0 = eb0*ib, cb1 = eb1*ib;
        float na = 0.f, nb = 0.f;
        float sa[8], sb[8];
#pragma unroll
        for (int i = 0; i < 8; ++i) {
            sa[i] = ca0*a0[i] + ca1*a1[i]; na += sa[i]*sa[i];
            sb[i] = cb0*t3[i] + cb1*t5[i]; nb += sb[i]*sb[i];
        }
        wave_sum2(na, nb);
        float sca = na / ((1.f + na) * (sqrtf(na) + 1e-9f));
        float scb = nb / ((1.f + nb) * (sqrtf(nb) + 1e-9f));
#pragma unroll
        for (int i = 0; i < 8; ++i) { va[i] = sca*sa[i]; vb[i] = scb*sb[i]; }
        if (it < 2) {
            float da0=0.f, da1=0.f, db0=0.f, db1=0.f;
#pragma unroll
            for (int i = 0; i < 8; ++i) {
                da0 += a0[i]*va[i]; da1 += a1[i]*va[i];
                db0 += t3[i]*vb[i]; db1 += t5[i]*vb[i];
            }
            wave_sum4(da0, da1, db0, db1);
            ba0 += da0; ba1 += da1; bb0 += db0; bb1 += db1;
        }
    }
    u16x8 pa, pb;
#pragma unroll
    for (int i = 0; i < 8; ++i) { pa[i] = f2bf(va[i]); pb[i] = f2bf(vb[i]); }
    *(u16x8*)(vs + (size_t)p*DPAD + c0) = pa;
    *(u16x8*)(vt + (size_t)p*DPAD + c0) = pb;
}

// ---------------------------------------------------------------------------
// Kernel 1b: transpose padded rows [n][l][520] -> V tiles [n][kb][512ch][32slot]
// with keys interleaved: slot s holds key (s>>1) + 16*(s&1).
// ---------------------------------------------------------------------------
__global__ __launch_bounds__(256) void transpose_vtile(
    const u16* __restrict__ vs, const u16* __restrict__ vt,
    u16* __restrict__ vsTt, u16* __restrict__ vtTt)
{
    __shared__ u16 T[64][65];
    const int z = blockIdx.z;
    const u16* src = ((z & 8) ? vt : vs) + (size_t)(z & 7) * LSEQ * DPAD;
    u16*       dst = ((z & 8) ? vtTt : vsTt) + (size_t)(z & 7) * 64 * DCH * 32;
    const int l0 = blockIdx.y * 64, c0 = blockIdx.x * 64;
    const int tid = threadIdx.x;
    const int rl = tid >> 3, cc = (tid & 7) * 8;
#pragma unroll
    for (int i = 0; i < 2; ++i) {
        int row = rl + i*32;
        *(u16x8*)(&T[row][cc]) = *(const u16x8*)(src + (size_t)(l0+row)*DPAD + c0 + cc);
    }
    __syncthreads();
    const int ch = tid >> 3;            // 0..31
    const int q3 = tid & 7;
    const int tt = q3 >> 2;             // which 32-key tile of this 64-row strip
    const int sc = (q3 & 3) * 8;        // slot base 0,8,16,24
#pragma unroll
    for (int i = 0; i < 2; ++i) {
        int c = ch + i*32;
        u16x8 o;
#pragma unroll
        for (int j = 0; j < 8; ++j) {
            int s = sc + j;
            int key = (s >> 1) + ((s & 1) << 4);   // interleave
            o[j] = T[tt*32 + key][c];
        }
        *(u16x8*)(dst + (size_t)(blockIdx.y*2 + tt) * (DCH*32)
                      + (size_t)(c0 + c) * 32 + sc) = o;
    }
}

// ---------------------------------------------------------------------------
// Kernel 2: windowed causal attention, fixed-max softmax, overlapped DMA.
// grid (32 strips, 16 instances), 256 threads (4 waves), 64 q-rows/block.
// ---------------------------------------------------------------------------
__global__ __launch_bounds__(256) void attn(
    const u16* __restrict__ vs, const u16* __restrict__ vt,
    const u16* __restrict__ vsTt, const u16* __restrict__ vtTt,
    u16* __restrict__ cat)
{
    __shared__ u16 Ks[33792/2];            // 32 rows x 1040B + 512B DMA slack
    __shared__ u16 Vs[DCH*32];             // 32 KB, [ch][slot] interleaved keys
    __shared__ unsigned int Ps32[4][16][20]; // per-wave P, packed pairs, pad->20

    const int inst = blockIdx.y;
    const int t = inst >> 3, n = inst & 7;
    const u16* src  = (t ? vt : vs) + (size_t)n * LSEQ * DPAD;
    const u16* srcT = (t ? vtTt : vsTt) + (size_t)n * 64 * DCH * 32;

    const int bx = blockIdx.x;
    const int r0 = (((bx & 7) << 2) | (bx >> 3)) * 64;   // XCD swizzle

    const int tid  = threadIdx.x;
    const int wid  = tid >> 6, lane = tid & 63;
    const int l16  = lane & 15, quad = lane >> 4;

    // Q A-frags register-resident
    bf16x8 qf[16];
    {
        const u16* qp = src + (size_t)(r0 + wid*16 + l16) * DPAD + quad*8;
#pragma unroll
        for (int kc = 0; kc < 16; ++kc) qf[kc] = *(const bf16x8*)(qp + kc*32);
    }

    f32x4 O[32];
#pragma unroll
    for (int i = 0; i < 32; ++i) O[i] = (f32x4){0.f, 0.f, 0.f, 0.f};
    f32x4 O2 = {0.f, 0.f, 0.f, 0.f};       // row sums via ones-MFMA

    bf16x8 ones8;
#pragma unroll
    for (int i = 0; i < 8; ++i) ones8[i] = (short)0x3F80;   // bf16 1.0

    const int kb_hi = (r0 >> 5) + 1;
    const int kb_lo = (kb_hi >= WTILES) ? kb_hi - (WTILES-1) : 0;

    // prologue: K(kb_lo) in flight
    {
        const u16* gK = src + (size_t)kb_lo * 32 * DPAD;
        for (int i = wid; i < 33; i += 4) dma16(gK + i*512 + lane*8, Ks + i*512);
    }

    for (int kb = kb_lo; kb <= kb_hi; ++kb) {
        __syncthreads();   // drains K(kb); separates prev Phase B reads from V(kb)
        // V(kb) DMA overlaps Phase A
        {
            const u16* gV = srcT + (size_t)kb * (DCH*32);
            for (int i = wid; i < 32; i += 4) dma16(gV + i*512 + lane*8, Vs + i*512);
        }

        // Phase A: S[16x32] = Q * K^T from LDS K mirror
        f32x4 S0 = {0.f,0.f,0.f,0.f}, S1 = {0.f,0.f,0.f,0.f};
#pragma unroll
        for (int kc = 0; kc < 16; ++kc) {
            bf16x8 b0 = *(const bf16x8*)(Ks + (size_t)l16*DPAD + kc*32 + quad*8);
            bf16x8 b1 = *(const bf16x8*)(Ks + (size_t)(16+l16)*DPAD + kc*32 + quad*8);
            S0 = __builtin_amdgcn_mfma_f32_16x16x32_bf16(qf[kc], b0, S0, 0, 0, 0);
            S1 = __builtin_amdgcn_mfma_f32_16x16x32_bf16(qf[kc], b1, S1, 0, 0, 0);
        }

        // fixed-max softmax: p = exp(s - 1 - 0.2*d), zero outside causal window
        const int rowg = r0 + wid*16 + quad*4;
#pragma unroll
        for (int r = 0; r < 4; ++r) {
            int row = rowg + r;
            int d0  = row - (kb*32 + l16);
            int d1  = d0 - 16;
            float p0 = (d0 >= 0) ? __expf(fmaf(-DECAYF, (float)d0, S0[r] - 1.f)) : 0.f;
            float p1 = (d1 >= 0) ? __expf(fmaf(-DECAYF, (float)d1, S1[r] - 1.f)) : 0.f;
            Ps32[wid][quad*4 + r][l16] = ((unsigned)f2bf(p1) << 16) | (unsigned)f2bf(p0);
        }

        __syncthreads();   // all waves done with Ks; drains V(kb)
        // K(kb+1) DMA overlaps Phase B
        if (kb < kb_hi) {
            const u16* gK = src + (size_t)(kb+1) * 32 * DPAD;
            for (int i = wid; i < 33; i += 4) dma16(gK + i*512 + lane*8, Ks + i*512);
        }

        // Phase B: O += P * V (interleaved slots consistent in Ps & Vs)
        bf16x8 pf = *(const bf16x8*)(&Ps32[wid][l16][quad*4]);
#pragma unroll
        for (int ct = 0; ct < 32; ++ct) {
            bf16x8 vf = *(const bf16x8*)(Vs + (size_t)(ct*16 + l16)*32 + quad*8);
            O[ct] = __builtin_amdgcn_mfma_f32_16x16x32_bf16(pf, vf, O[ct], 0, 0, 0);
        }
        O2 = __builtin_amdgcn_mfma_f32_16x16x32_bf16(pf, ones8, O2, 0, 0, 0);
    }

    // epilogue: O /= rowsum, write bf16 into cat
    float inv[4];
#pragma unroll
    for (int r = 0; r < 4; ++r) inv[r] = 1.f / O2[r];
    const size_t rowbase = (size_t)n * LSEQ + r0 + wid*16 + quad*4;
    const int colbase = t * 512 + l16;
#pragma unroll
    for (int ct = 0; ct < 32; ++ct) {
#pragma unroll
        for (int r = 0; r < 4; ++r)
            cat[(rowbase + r) * 1024 + colbase + ct*16] = f2bf(O[ct][r] * inv[r]);
    }
}

// ---------------------------------------------------------------------------
// Kernel 3: out[16384,512] = cat[16384,1024] @ W[512,1024]^T + bias (fp32 out)
// W read as fp32 and converted during staging (cast_w folded in).
// ---------------------------------------------------------------------------
__global__ __launch_bounds__(256) void fusion_gemm(
    const u16* __restrict__ A, const float* __restrict__ W,
    const float* __restrict__ bias, float* __restrict__ out)
{
    __shared__ u16 As[128][72];
    __shared__ u16 Bs[128][72];
    const int m0 = blockIdx.x * 128;
    const int n0 = blockIdx.y * 128;
    const int tid = threadIdx.x;
    const int wid = tid >> 6, lane = tid & 63;
    const int l16 = lane & 15, quad = lane >> 4;
    const int wm = (wid >> 1) * 64, wn = (wid & 1) * 64;

    f32x4 acc[4][4];
#pragma unroll
    for (int i = 0; i < 4; ++i)
#pragma unroll
        for (int j = 0; j < 4; ++j) acc[i][j] = (f32x4){0.f, 0.f, 0.f, 0.f};

    for (int kb = 0; kb < 16; ++kb) {
#pragma unroll
        for (int i = 0; i < 4; ++i) {
            int id = tid + i*256;
            int row = id >> 3, kc = id & 7;
            *(u16x8*)(&As[row][kc*8]) = *(const u16x8*)(A + (size_t)(m0+row)*1024 + kb*64 + kc*8);
            const float4* wp = (const float4*)(W + (size_t)(n0+row)*1024 + kb*64 + kc*8);
            float4 wa = wp[0], wb4 = wp[1];
            u16x8 bb;
            bb[0]=f2bf(wa.x); bb[1]=f2bf(wa.y); bb[2]=f2bf(wa.z); bb[3]=f2bf(wa.w);
            bb[4]=f2bf(wb4.x); bb[5]=f2bf(wb4.y); bb[6]=f2bf(wb4.z); bb[7]=f2bf(wb4.w);
            *(u16x8*)(&Bs[row][kc*8]) = bb;
        }
        __syncthreads();
#pragma unroll
        for (int k2 = 0; k2 < 2; ++k2) {
            bf16x8 af[4], bfr[4];
#pragma unroll
            for (int i = 0; i < 4; ++i) {
                af[i]  = *(const bf16x8*)(&As[wm + i*16 + l16][k2*32 + quad*8]);
                bfr[i] = *(const bf16x8*)(&Bs[wn + i*16 + l16][k2*32 + quad*8]);
            }
#pragma unroll
            for (int i = 0; i < 4; ++i)
#pragma unroll
                for (int j = 0; j < 4; ++j)
                    acc[i][j] = __builtin_amdgcn_mfma_f32_16x16x32_bf16(af[i], bfr[j], acc[i][j], 0, 0, 0);
        }
        __syncthreads();
    }
#pragma unroll
    for (int j = 0; j < 4; ++j) {
        int col = n0 + wn + j*16 + l16;
        float bv = bias[col];
#pragma unroll
        for (int i = 0; i < 4; ++i) {
            int rowb = m0 + wm + i*16 + quad*4;
#pragma unroll
            for (int r = 0; r < 4; ++r)
                out[(size_t)(rowb + r)*512 + col] = acc[i][j][r] + bv;
        }
    }
}

// ---------------------------------------------------------------------------
extern "C" void kernel_launch(void* const* d_in, const int* in_sizes, int n_in,
                              void* d_out, int out_size, void* d_ws, size_t ws_size,
                              hipStream_t stream)
{
    (void)in_sizes; (void)n_in; (void)out_size; (void)ws_size;
    const float* x  = (const float*)d_in[0];
    const float* w3 = (const float*)d_in[1];
    const float* w5 = (const float*)d_in[2];
    const float* fw = (const float*)d_in[3];
    const float* fb = (const float*)d_in[4];
    float* out = (float*)d_out;

    const size_t SZP = (size_t)NBATCH * LSEQ * DPAD;    // padded rows
    const size_t SZT = (size_t)NBATCH * 64 * DCH * 32;  // V tiles
    u16* vs   = (u16*)d_ws;        // [N][L][520]
    u16* vt   = vs   + SZP;
    u16* vsTt = vt   + SZP;        // [N][64][512][32] (interleaved keys)
    u16* vtTt = vsTt + SZT;
    u16* cat  = vtTt + SZT;        // [N*L][1024]

    conv_route    <<<4096, 256, 0, stream>>>(x, w3, w5, vs, vt);
    transpose_vtile<<<dim3(8, 32, 16), 256, 0, stream>>>(vs, vt, vsTt, vtTt);
    attn          <<<dim3(32, 16), 256, 0, stream>>>(vs, vt, vsTt, vtTt, cat);
    fusion_gemm   <<<dim3(128, 4), 256, 0, stream>>>(cat, fw, fb, out);
}

// Round 5
// 193.099 us; speedup vs baseline: 5.3789x; 1.0366x over previous
//
#include <hip/hip_runtime.h>

// ---------------------------------------------------------------------------
// capsule_87840671138361: conv->routing->attention->fusion, MI355X (gfx950)
// R5 changes vs R4:
//  - conv_route: QUADRATIC-FORM routing. Dynamic routing depends on u only
//    via Gram dots A=u0.u0, B=u0.u1, C=u1.u1: n2 = c0^2 A + 2 c0 c1 B + c1^2 C,
//    logit updates u0.v = sc(c0 A + c1 B), u1.v = sc(c0 B + c1 C). One 6-value
//    wave reduction total (was 5 full reductions); per-channel work = single
//    final combine. Kernel becomes memory-bound.
//  - attn: W=4 key-tiles (64-key min window; truncated relative mass ~4e-5,
//    output err ~3e-5 << threshold margin). 32% fewer tiles.
//  - attn: Phase A split into 4 independent 8-deep MFMA chains (was 2x16-deep)
//    to cover MFMA latency.
// ---------------------------------------------------------------------------

typedef short     bf16x8 __attribute__((ext_vector_type(8)));  // MFMA A/B frag
typedef float     f32x4  __attribute__((ext_vector_type(4)));  // MFMA C/D frag
typedef unsigned short u16;
typedef u16       u16x8  __attribute__((ext_vector_type(8)));

#define NBATCH 8
#define LSEQ   2048
#define DCH    512
#define DPAD   520      // padded row stride (elems): 1040B, 4-bank row shift
#define DECAYF 0.2f
#define WTILES 4        // 64-key min window; truncated mass ~4e-5 relative

typedef const __attribute__((address_space(1))) unsigned char* gas_t;
typedef __attribute__((address_space(3))) unsigned char* las_t;
__device__ __forceinline__ void dma16(const void* g, void* l) {
    __builtin_amdgcn_global_load_lds((gas_t)g, (las_t)l, 16, 0, 0);
}

__device__ __forceinline__ u16 f2bf(float f) {
    unsigned int u = __float_as_uint(f);
    u += 0x7fffu + ((u >> 16) & 1u);   // RNE; inputs never NaN
    return (u16)(u >> 16);
}

__device__ __forceinline__ void wave_sum6(float& a, float& b, float& c,
                                          float& d, float& e, float& f) {
#pragma unroll
    for (int m = 1; m < 64; m <<= 1) {
        float ta = __shfl_xor(a, m, 64);
        float tb = __shfl_xor(b, m, 64);
        float tc = __shfl_xor(c, m, 64);
        float td = __shfl_xor(d, m, 64);
        float te = __shfl_xor(e, m, 64);
        float tf = __shfl_xor(f, m, 64);
        a += ta; b += tb; c += tc; d += td; e += te; f += tf;
    }
}

// ---------------------------------------------------------------------------
// Kernel 1: causal depthwise conv (k=3,5) + 2x dynamic routing via Gram dots.
// One wave per (n,l); lane owns 8 channels.
// ---------------------------------------------------------------------------
__global__ __launch_bounds__(256) void conv_route(
    const float* __restrict__ x, const float* __restrict__ w3, const float* __restrict__ w5,
    u16* __restrict__ vs, u16* __restrict__ vt)
{
    const int wid  = threadIdx.x >> 6;
    const int lane = threadIdx.x & 63;
    const int p = blockIdx.x * 4 + wid;          // 16384 positions
    const int n = p >> 11, l = p & (LSEQ - 1);
    const int c0 = lane * 8;

    float xm[5][8];                              // xm[j][i] = x[l-j][c0+i]
#pragma unroll
    for (int j = 0; j < 5; ++j) {
        int ll = l - j;
        if (ll >= 0) {                           // wave-uniform branch
            const float4* sp = (const float4*)(x + ((size_t)(n*LSEQ + ll))*DCH + c0);
            float4 a = sp[0], b = sp[1];
            xm[j][0]=a.x; xm[j][1]=a.y; xm[j][2]=a.z; xm[j][3]=a.w;
            xm[j][4]=b.x; xm[j][5]=b.y; xm[j][6]=b.z; xm[j][7]=b.w;
        } else {
#pragma unroll
            for (int i = 0; i < 8; ++i) xm[j][i] = 0.f;
        }
    }
    float f3[24], f5[40];
#pragma unroll
    for (int k = 0; k < 6; ++k)  ((float4*)f3)[k] = ((const float4*)(w3 + (size_t)c0*3))[k];
#pragma unroll
    for (int k = 0; k < 10; ++k) ((float4*)f5)[k] = ((const float4*)(w5 + (size_t)c0*5))[k];

    float t3[8], t5[8], a0[8], a1[8];
#pragma unroll
    for (int i = 0; i < 8; ++i) {
        t3[i] = f3[i*3+0]*xm[2][i] + f3[i*3+1]*xm[1][i] + f3[i*3+2]*xm[0][i];
        t5[i] = f5[i*5+0]*xm[4][i] + f5[i*5+1]*xm[3][i] + f5[i*5+2]*xm[2][i]
              + f5[i*5+3]*xm[1][i] + f5[i*5+4]*xm[0][i];
        a0[i] = xm[0][i] - t3[i];                // seasonal u0
        a1[i] = xm[0][i] - t5[i];                // seasonal u1
    }

    // Gram dots for both routings (seasonal: a0,a1 ; trend: t3,t5)
    float A1=0.f, B1=0.f, C1=0.f, A2=0.f, B2=0.f, C2=0.f;
#pragma unroll
    for (int i = 0; i < 8; ++i) {
        A1 += a0[i]*a0[i]; B1 += a0[i]*a1[i]; C1 += a1[i]*a1[i];
        A2 += t3[i]*t3[i]; B2 += t3[i]*t5[i]; C2 += t5[i]*t5[i];
    }
    wave_sum6(A1, B1, C1, A2, B2, C2);

    // 3 routing iterations, fully scalar via quadratic forms
    float ba0=0.f, ba1=0.f, bb0=0.f, bb1=0.f;
    float ca0=0.5f, ca1=0.5f, sca=0.f, cb0=0.5f, cb1=0.5f, scb=0.f;
#pragma unroll
    for (int it = 0; it < 3; ++it) {
        float mxa = fmaxf(ba0, ba1), mxb = fmaxf(bb0, bb1);
        float ea0 = __expf(ba0-mxa), ea1 = __expf(ba1-mxa);
        float eb0 = __expf(bb0-mxb), eb1 = __expf(bb1-mxb);
        float ia = 1.f/(ea0+ea1), ib = 1.f/(eb0+eb1);
        ca0 = ea0*ia; ca1 = ea1*ia; cb0 = eb0*ib; cb1 = eb1*ib;
        float na = ca0*ca0*A1 + 2.f*ca0*ca1*B1 + ca1*ca1*C1;
        float nb = cb0*cb0*A2 + 2.f*cb0*cb1*B2 + cb1*cb1*C2;
        sca = na / ((1.f + na) * (sqrtf(na) + 1e-9f));
        scb = nb / ((1.f + nb) * (sqrtf(nb) + 1e-9f));
        if (it < 2) {
            ba0 += sca*(ca0*A1 + ca1*B1);
            ba1 += sca*(ca0*B1 + ca1*C1);
            bb0 += scb*(cb0*A2 + cb1*B2);
            bb1 += scb*(cb0*B2 + cb1*C2);
        }
    }
    // final combine per channel
    u16x8 pa, pb;
#pragma unroll
    for (int i = 0; i < 8; ++i) {
        pa[i] = f2bf(sca*(ca0*a0[i] + ca1*a1[i]));
        pb[i] = f2bf(scb*(cb0*t3[i] + cb1*t5[i]));
    }
    *(u16x8*)(vs + (size_t)p*DPAD + c0) = pa;
    *(u16x8*)(vt + (size_t)p*DPAD + c0) = pb;
}

// ---------------------------------------------------------------------------
// Kernel 1b: transpose padded rows [n][l][520] -> V tiles [n][kb][512ch][32slot]
// with keys interleaved: slot s holds key (s>>1) + 16*(s&1).
// ---------------------------------------------------------------------------
__global__ __launch_bounds__(256) void transpose_vtile(
    const u16* __restrict__ vs, const u16* __restrict__ vt,
    u16* __restrict__ vsTt, u16* __restrict__ vtTt)
{
    __shared__ u16 T[64][65];
    const int z = blockIdx.z;
    const u16* src = ((z & 8) ? vt : vs) + (size_t)(z & 7) * LSEQ * DPAD;
    u16*       dst = ((z & 8) ? vtTt : vsTt) + (size_t)(z & 7) * 64 * DCH * 32;
    const int l0 = blockIdx.y * 64, c0 = blockIdx.x * 64;
    const int tid = threadIdx.x;
    const int rl = tid >> 3, cc = (tid & 7) * 8;
#pragma unroll
    for (int i = 0; i < 2; ++i) {
        int row = rl + i*32;
        *(u16x8*)(&T[row][cc]) = *(const u16x8*)(src + (size_t)(l0+row)*DPAD + c0 + cc);
    }
    __syncthreads();
    const int ch = tid >> 3;            // 0..31
    const int q3 = tid & 7;
    const int tt = q3 >> 2;             // which 32-key tile of this 64-row strip
    const int sc = (q3 & 3) * 8;        // slot base 0,8,16,24
#pragma unroll
    for (int i = 0; i < 2; ++i) {
        int c = ch + i*32;
        u16x8 o;
#pragma unroll
        for (int j = 0; j < 8; ++j) {
            int s = sc + j;
            int key = (s >> 1) + ((s & 1) << 4);   // interleave
            o[j] = T[tt*32 + key][c];
        }
        *(u16x8*)(dst + (size_t)(blockIdx.y*2 + tt) * (DCH*32)
                      + (size_t)(c0 + c) * 32 + sc) = o;
    }
}

// ---------------------------------------------------------------------------
// Kernel 2: windowed causal attention, fixed-max softmax, overlapped DMA.
// grid (32 strips, 16 instances), 256 threads (4 waves), 64 q-rows/block.
// ---------------------------------------------------------------------------
__global__ __launch_bounds__(256) void attn(
    const u16* __restrict__ vs, const u16* __restrict__ vt,
    const u16* __restrict__ vsTt, const u16* __restrict__ vtTt,
    u16* __restrict__ cat)
{
    __shared__ u16 Ks[33792/2];            // 32 rows x 1040B + 512B DMA slack
    __shared__ u16 Vs[DCH*32];             // 32 KB, [ch][slot] interleaved keys
    __shared__ unsigned int Ps32[4][16][20]; // per-wave P, packed pairs, pad->20

    const int inst = blockIdx.y;
    const int t = inst >> 3, n = inst & 7;
    const u16* src  = (t ? vt : vs) + (size_t)n * LSEQ * DPAD;
    const u16* srcT = (t ? vtTt : vsTt) + (size_t)n * 64 * DCH * 32;

    const int bx = blockIdx.x;
    const int r0 = (((bx & 7) << 2) | (bx >> 3)) * 64;   // XCD swizzle

    const int tid  = threadIdx.x;
    const int wid  = tid >> 6, lane = tid & 63;
    const int l16  = lane & 15, quad = lane >> 4;

    // Q A-frags register-resident
    bf16x8 qf[16];
    {
        const u16* qp = src + (size_t)(r0 + wid*16 + l16) * DPAD + quad*8;
#pragma unroll
        for (int kc = 0; kc < 16; ++kc) qf[kc] = *(const bf16x8*)(qp + kc*32);
    }

    f32x4 O[32];
#pragma unroll
    for (int i = 0; i < 32; ++i) O[i] = (f32x4){0.f, 0.f, 0.f, 0.f};
    f32x4 O2 = {0.f, 0.f, 0.f, 0.f};       // row sums via ones-MFMA

    bf16x8 ones8;
#pragma unroll
    for (int i = 0; i < 8; ++i) ones8[i] = (short)0x3F80;   // bf16 1.0

    const int kb_hi = (r0 >> 5) + 1;
    const int kb_lo = (kb_hi >= WTILES) ? kb_hi - (WTILES-1) : 0;

    // prologue: K(kb_lo) in flight
    {
        const u16* gK = src + (size_t)kb_lo * 32 * DPAD;
        for (int i = wid; i < 33; i += 4) dma16(gK + i*512 + lane*8, Ks + i*512);
    }

    for (int kb = kb_lo; kb <= kb_hi; ++kb) {
        __syncthreads();   // drains K(kb); separates prev Phase B reads from V(kb)
        // V(kb) DMA overlaps Phase A
        {
            const u16* gV = srcT + (size_t)kb * (DCH*32);
            for (int i = wid; i < 32; i += 4) dma16(gV + i*512 + lane*8, Vs + i*512);
        }

        // Phase A: S[16x32] = Q * K^T, 4 independent 8-deep chains
        f32x4 S0a = {0.f,0.f,0.f,0.f}, S1a = {0.f,0.f,0.f,0.f};
        f32x4 S0b = {0.f,0.f,0.f,0.f}, S1b = {0.f,0.f,0.f,0.f};
#pragma unroll
        for (int kc = 0; kc < 8; ++kc) {
            bf16x8 b0 = *(const bf16x8*)(Ks + (size_t)l16*DPAD + kc*32 + quad*8);
            bf16x8 b1 = *(const bf16x8*)(Ks + (size_t)(16+l16)*DPAD + kc*32 + quad*8);
            S0a = __builtin_amdgcn_mfma_f32_16x16x32_bf16(qf[kc], b0, S0a, 0, 0, 0);
            S1a = __builtin_amdgcn_mfma_f32_16x16x32_bf16(qf[kc], b1, S1a, 0, 0, 0);
        }
#pragma unroll
        for (int kc = 8; kc < 16; ++kc) {
            bf16x8 b0 = *(const bf16x8*)(Ks + (size_t)l16*DPAD + kc*32 + quad*8);
            bf16x8 b1 = *(const bf16x8*)(Ks + (size_t)(16+l16)*DPAD + kc*32 + quad*8);
            S0b = __builtin_amdgcn_mfma_f32_16x16x32_bf16(qf[kc], b0, S0b, 0, 0, 0);
            S1b = __builtin_amdgcn_mfma_f32_16x16x32_bf16(qf[kc], b1, S1b, 0, 0, 0);
        }
        f32x4 S0 = S0a + S0b, S1 = S1a + S1b;

        // fixed-max softmax: p = exp(s - 1 - 0.2*d), zero outside causal window
        const int rowg = r0 + wid*16 + quad*4;
#pragma unroll
        for (int r = 0; r < 4; ++r) {
            int row = rowg + r;
            int d0  = row - (kb*32 + l16);
            int d1  = d0 - 16;
            float p0 = (d0 >= 0) ? __expf(fmaf(-DECAYF, (float)d0, S0[r] - 1.f)) : 0.f;
            float p1 = (d1 >= 0) ? __expf(fmaf(-DECAYF, (float)d1, S1[r] - 1.f)) : 0.f;
            Ps32[wid][quad*4 + r][l16] = ((unsigned)f2bf(p1) << 16) | (unsigned)f2bf(p0);
        }

        __syncthreads();   // all waves done with Ks; drains V(kb)
        // K(kb+1) DMA overlaps Phase B
        if (kb < kb_hi) {
            const u16* gK = src + (size_t)(kb+1) * 32 * DPAD;
            for (int i = wid; i < 33; i += 4) dma16(gK + i*512 + lane*8, Ks + i*512);
        }

        // Phase B: O += P * V (interleaved slots consistent in Ps & Vs)
        bf16x8 pf = *(const bf16x8*)(&Ps32[wid][l16][quad*4]);
#pragma unroll
        for (int ct = 0; ct < 32; ++ct) {
            bf16x8 vf = *(const bf16x8*)(Vs + (size_t)(ct*16 + l16)*32 + quad*8);
            O[ct] = __builtin_amdgcn_mfma_f32_16x16x32_bf16(pf, vf, O[ct], 0, 0, 0);
        }
        O2 = __builtin_amdgcn_mfma_f32_16x16x32_bf16(pf, ones8, O2, 0, 0, 0);
    }

    // epilogue: O /= rowsum, write bf16 into cat
    float inv[4];
#pragma unroll
    for (int r = 0; r < 4; ++r) inv[r] = 1.f / O2[r];
    const size_t rowbase = (size_t)n * LSEQ + r0 + wid*16 + quad*4;
    const int colbase = t * 512 + l16;
#pragma unroll
    for (int ct = 0; ct < 32; ++ct) {
#pragma unroll
        for (int r = 0; r < 4; ++r)
            cat[(rowbase + r) * 1024 + colbase + ct*16] = f2bf(O[ct][r] * inv[r]);
    }
}

// ---------------------------------------------------------------------------
// Kernel 3: out[16384,512] = cat[16384,1024] @ W[512,1024]^T + bias (fp32 out)
// W read as fp32 and converted during staging.
// ---------------------------------------------------------------------------
__global__ __launch_bounds__(256) void fusion_gemm(
    const u16* __restrict__ A, const float* __restrict__ W,
    const float* __restrict__ bias, float* __restrict__ out)
{
    __shared__ u16 As[128][72];
    __shared__ u16 Bs[128][72];
    const int m0 = blockIdx.x * 128;
    const int n0 = blockIdx.y * 128;
    const int tid = threadIdx.x;
    const int wid = tid >> 6, lane = tid & 63;
    const int l16 = lane & 15, quad = lane >> 4;
    const int wm = (wid >> 1) * 64, wn = (wid & 1) * 64;

    f32x4 acc[4][4];
#pragma unroll
    for (int i = 0; i < 4; ++i)
#pragma unroll
        for (int j = 0; j < 4; ++j) acc[i][j] = (f32x4){0.f, 0.f, 0.f, 0.f};

    for (int kb = 0; kb < 16; ++kb) {
#pragma unroll
        for (int i = 0; i < 4; ++i) {
            int id = tid + i*256;
            int row = id >> 3, kc = id & 7;
            *(u16x8*)(&As[row][kc*8]) = *(const u16x8*)(A + (size_t)(m0+row)*1024 + kb*64 + kc*8);
            const float4* wp = (const float4*)(W + (size_t)(n0+row)*1024 + kb*64 + kc*8);
            float4 wa = wp[0], wb4 = wp[1];
            u16x8 bb;
            bb[0]=f2bf(wa.x); bb[1]=f2bf(wa.y); bb[2]=f2bf(wa.z); bb[3]=f2bf(wa.w);
            bb[4]=f2bf(wb4.x); bb[5]=f2bf(wb4.y); bb[6]=f2bf(wb4.z); bb[7]=f2bf(wb4.w);
            *(u16x8*)(&Bs[row][kc*8]) = bb;
        }
        __syncthreads();
#pragma unroll
        for (int k2 = 0; k2 < 2; ++k2) {
            bf16x8 af[4], bfr[4];
#pragma unroll
            for (int i = 0; i < 4; ++i) {
                af[i]  = *(const bf16x8*)(&As[wm + i*16 + l16][k2*32 + quad*8]);
                bfr[i] = *(const bf16x8*)(&Bs[wn + i*16 + l16][k2*32 + quad*8]);
            }
#pragma unroll
            for (int i = 0; i < 4; ++i)
#pragma unroll
                for (int j = 0; j < 4; ++j)
                    acc[i][j] = __builtin_amdgcn_mfma_f32_16x16x32_bf16(af[i], bfr[j], acc[i][j], 0, 0, 0);
        }
        __syncthreads();
    }
#pragma unroll
    for (int j = 0; j < 4; ++j) {
        int col = n0 + wn + j*16 + l16;
        float bv = bias[col];
#pragma unroll
        for (int i = 0; i < 4; ++i) {
            int rowb = m0 + wm + i*16 + quad*4;
#pragma unroll
            for (int r = 0; r < 4; ++r)
                out[(size_t)(rowb + r)*512 + col] = acc[i][j][r] + bv;
        }
    }
}

// ---------------------------------------------------------------------------
extern "C" void kernel_launch(void* const* d_in, const int* in_sizes, int n_in,
                              void* d_out, int out_size, void* d_ws, size_t ws_size,
                              hipStream_t stream)
{
    (void)in_sizes; (void)n_in; (void)out_size; (void)ws_size;
    const float* x  = (const float*)d_in[0];
    const float* w3 = (const float*)d_in[1];
    const float* w5 = (const float*)d_in[2];
    const float* fw = (const float*)d_in[3];
    const float* fb = (const float*)d_in[4];
    float* out = (float*)d_out;

    const size_t SZP = (size_t)NBATCH * LSEQ * DPAD;    // padded rows
    const size_t SZT = (size_t)NBATCH * 64 * DCH * 32;  // V tiles
    u16* vs   = (u16*)d_ws;        // [N][L][520]
    u16* vt   = vs   + SZP;
    u16* vsTt = vt   + SZP;        // [N][64][512][32] (interleaved keys)
    u16* vtTt = vsTt + SZT;
    u16* cat  = vtTt + SZT;        // [N*L][1024]

    conv_route    <<<4096, 256, 0, stream>>>(x, w3, w5, vs, vt);
    transpose_vtile<<<dim3(8, 32, 16), 256, 0, stream>>>(vs, vt, vsTt, vtTt);
    attn          <<<dim3(32, 16), 256, 0, stream>>>(vs, vt, vsTt, vtTt, cat);
    fusion_gemm   <<<dim3(128, 4), 256, 0, stream>>>(cat, fw, fb, out);
}

// Round 6
// 171.169 us; speedup vs baseline: 6.0680x; 1.1281x over previous
//
#include <hip/hip_runtime.h>

// ---------------------------------------------------------------------------
// capsule_87840671138361: conv->routing->attention->fusion, MI355X (gfx950)
// R6 changes vs R5:
//  - fusion_gemm: separate cast_w again (no fp32 W convert in k-loop, was
//    128x redundant); A/W staged via global_load_lds w=16; XOR-swizzled LDS
//    (swizzle folded into per-lane DMA source addresses -> conflict-free
//    ds_read_b128 without padding); 64x128 tiles, grid 1024 (4 blocks/CU).
//  - conv_route absorbs transpose_vtile: block = 32 aligned positions
//    (8 waves x 4 pos, rolling conv window), results staged in LDS
//    (row stride 524: V^T gather is bank-even), block writes both the
//    row-major vs/vt AND the interleaved V^T tile. Kernel + 132MB traffic
//    eliminated.
//  - attn unchanged from R5.
// ---------------------------------------------------------------------------

typedef short     bf16x8 __attribute__((ext_vector_type(8)));  // MFMA A/B frag
typedef float     f32x4  __attribute__((ext_vector_type(4)));  // MFMA C/D frag
typedef unsigned short u16;
typedef u16       u16x8  __attribute__((ext_vector_type(8)));
typedef u16       u16x4  __attribute__((ext_vector_type(4)));

#define NBATCH 8
#define LSEQ   2048
#define DCH    512
#define DPAD   520      // padded global row stride (elems): 1040B
#define TPAD   524      // conv LDS row stride: 6-bank/row shift -> gather even
#define DECAYF 0.2f
#define WTILES 4        // 64-key min window; truncated mass ~4e-5 relative

typedef const __attribute__((address_space(1))) unsigned char* gas_t;
typedef __attribute__((address_space(3))) unsigned char* las_t;
__device__ __forceinline__ void dma16(const void* g, void* l) {
    __builtin_amdgcn_global_load_lds((gas_t)g, (las_t)l, 16, 0, 0);
}

__device__ __forceinline__ u16 f2bf(float f) {
    unsigned int u = __float_as_uint(f);
    u += 0x7fffu + ((u >> 16) & 1u);   // RNE; inputs never NaN
    return (u16)(u >> 16);
}

__device__ __forceinline__ void wave_sum6(float& a, float& b, float& c,
                                          float& d, float& e, float& f) {
#pragma unroll
    for (int m = 1; m < 64; m <<= 1) {
        float ta = __shfl_xor(a, m, 64);
        float tb = __shfl_xor(b, m, 64);
        float tc = __shfl_xor(c, m, 64);
        float td = __shfl_xor(d, m, 64);
        float te = __shfl_xor(e, m, 64);
        float tf = __shfl_xor(f, m, 64);
        a += ta; b += tb; c += tc; d += td; e += te; f += tf;
    }
}

// ---------------------------------------------------------------------------
// Kernel 1: conv(k=3,5) + 2x quadratic-form routing + fused V^T tile emit.
// 512 threads = 8 waves x 4 positions; block covers 32 aligned positions
// (= one 32-key V tile per tensor). Rolling 5-row window per wave.
// ---------------------------------------------------------------------------
__global__ __launch_bounds__(512) void conv_route(
    const float* __restrict__ x, const float* __restrict__ w3, const float* __restrict__ w5,
    u16* __restrict__ vs, u16* __restrict__ vt,
    u16* __restrict__ vsTt, u16* __restrict__ vtTt)
{
    __shared__ u16 Ts[2][32][TPAD];

    const int tid  = threadIdx.x;
    const int wid  = tid >> 6, lane = tid & 63;
    const int pb   = blockIdx.x * 32 + wid * 4;    // first position of wave
    const int n    = pb >> 11;
    const int l0   = pb & (LSEQ - 1);
    const int c0   = lane * 8;

    float f3[24], f5[40];
#pragma unroll
    for (int k = 0; k < 6; ++k)  ((float4*)f3)[k] = ((const float4*)(w3 + (size_t)c0*3))[k];
#pragma unroll
    for (int k = 0; k < 10; ++k) ((float4*)f5)[k] = ((const float4*)(w5 + (size_t)c0*5))[k];

    // rolling window: xm[j][i] = x[l-j][c0+i]
    float xm[5][8];
#pragma unroll
    for (int j = 0; j < 5; ++j) {
        int ll = l0 - j;
        if (ll >= 0) {                              // wave-uniform branch
            const float4* sp = (const float4*)(x + ((size_t)(n*LSEQ + ll))*DCH + c0);
            float4 a = sp[0], b = sp[1];
            xm[j][0]=a.x; xm[j][1]=a.y; xm[j][2]=a.z; xm[j][3]=a.w;
            xm[j][4]=b.x; xm[j][5]=b.y; xm[j][6]=b.z; xm[j][7]=b.w;
        } else {
#pragma unroll
            for (int i = 0; i < 8; ++i) xm[j][i] = 0.f;
        }
    }

#pragma unroll
    for (int s = 0; s < 4; ++s) {
        const int l = l0 + s;
        if (s > 0) {   // shift window, load new row l
#pragma unroll
            for (int j = 4; j > 0; --j)
#pragma unroll
                for (int i = 0; i < 8; ++i) xm[j][i] = xm[j-1][i];
            const float4* sp = (const float4*)(x + ((size_t)(n*LSEQ + l))*DCH + c0);
            float4 a = sp[0], b = sp[1];
            xm[0][0]=a.x; xm[0][1]=a.y; xm[0][2]=a.z; xm[0][3]=a.w;
            xm[0][4]=b.x; xm[0][5]=b.y; xm[0][6]=b.z; xm[0][7]=b.w;
        }

        float t3[8], t5[8], a0[8], a1[8];
#pragma unroll
        for (int i = 0; i < 8; ++i) {
            t3[i] = f3[i*3+0]*xm[2][i] + f3[i*3+1]*xm[1][i] + f3[i*3+2]*xm[0][i];
            t5[i] = f5[i*5+0]*xm[4][i] + f5[i*5+1]*xm[3][i] + f5[i*5+2]*xm[2][i]
                  + f5[i*5+3]*xm[1][i] + f5[i*5+4]*xm[0][i];
            a0[i] = xm[0][i] - t3[i];
            a1[i] = xm[0][i] - t5[i];
        }

        float A1=0.f, B1=0.f, C1=0.f, A2=0.f, B2=0.f, C2=0.f;
#pragma unroll
        for (int i = 0; i < 8; ++i) {
            A1 += a0[i]*a0[i]; B1 += a0[i]*a1[i]; C1 += a1[i]*a1[i];
            A2 += t3[i]*t3[i]; B2 += t3[i]*t5[i]; C2 += t5[i]*t5[i];
        }
        wave_sum6(A1, B1, C1, A2, B2, C2);

        float ba0=0.f, ba1=0.f, bb0=0.f, bb1=0.f;
        float ca0=0.5f, ca1=0.5f, sca=0.f, cb0=0.5f, cb1=0.5f, scb=0.f;
#pragma unroll
        for (int it = 0; it < 3; ++it) {
            float mxa = fmaxf(ba0, ba1), mxb = fmaxf(bb0, bb1);
            float ea0 = __expf(ba0-mxa), ea1 = __expf(ba1-mxa);
            float eb0 = __expf(bb0-mxb), eb1 = __expf(bb1-mxb);
            float ia = 1.f/(ea0+ea1), ib = 1.f/(eb0+eb1);
            ca0 = ea0*ia; ca1 = ea1*ia; cb0 = eb0*ib; cb1 = eb1*ib;
            float na = ca0*ca0*A1 + 2.f*ca0*ca1*B1 + ca1*ca1*C1;
            float nb = cb0*cb0*A2 + 2.f*cb0*cb1*B2 + cb1*cb1*C2;
            sca = na / ((1.f + na) * (sqrtf(na) + 1e-9f));
            scb = nb / ((1.f + nb) * (sqrtf(nb) + 1e-9f));
            if (it < 2) {
                ba0 += sca*(ca0*A1 + ca1*B1);
                ba1 += sca*(ca0*B1 + ca1*C1);
                bb0 += scb*(cb0*A2 + cb1*B2);
                bb1 += scb*(cb0*B2 + cb1*C2);
            }
        }

        u16x8 pa, pb8;
#pragma unroll
        for (int i = 0; i < 8; ++i) {
            pa[i]  = f2bf(sca*(ca0*a0[i] + ca1*a1[i]));
            pb8[i] = f2bf(scb*(cb0*t3[i] + cb1*t5[i]));
        }
        *(u16x8*)(vs + (size_t)(pb + s)*DPAD + c0) = pa;
        *(u16x8*)(vt + (size_t)(pb + s)*DPAD + c0) = pb8;
        *(u16x8*)(&Ts[0][wid*4 + s][c0]) = pa;
        *(u16x8*)(&Ts[1][wid*4 + s][c0]) = pb8;
    }
    __syncthreads();

    // emit V^T tile [512 ch][32 interleaved slots] for both tensors.
    // chunk id = z*2048 + ch*4 + so ; 4096 chunks / 512 threads = 8 each.
#pragma unroll
    for (int k = 0; k < 8; ++k) {
        int id = k*512 + tid;
        int z = id >> 11, rem = id & 2047, ch = rem >> 2, so = rem & 3;
        u16x8 o;
#pragma unroll
        for (int j = 0; j < 8; ++j) {
            int s = so*8 + j;
            int key = (s >> 1) + ((s & 1) << 4);   // interleave
            o[j] = Ts[z][key][ch];
        }
        u16* dst = (z ? vtTt : vsTt) + (size_t)blockIdx.x * (DCH*32);
        *(u16x8*)(dst + ch*32 + so*8) = o;
    }
}

// ---------------------------------------------------------------------------
// Kernel 2: windowed causal attention (unchanged from R5).
// ---------------------------------------------------------------------------
__global__ __launch_bounds__(256) void attn(
    const u16* __restrict__ vs, const u16* __restrict__ vt,
    const u16* __restrict__ vsTt, const u16* __restrict__ vtTt,
    u16* __restrict__ cat)
{
    __shared__ u16 Ks[33792/2];            // 32 rows x 1040B + 512B DMA slack
    __shared__ u16 Vs[DCH*32];             // 32 KB, [ch][slot] interleaved keys
    __shared__ unsigned int Ps32[4][16][20]; // per-wave P, packed pairs, pad->20

    const int inst = blockIdx.y;
    const int t = inst >> 3, n = inst & 7;
    const u16* src  = (t ? vt : vs) + (size_t)n * LSEQ * DPAD;
    const u16* srcT = (t ? vtTt : vsTt) + (size_t)n * 64 * DCH * 32;

    const int bx = blockIdx.x;
    const int r0 = (((bx & 7) << 2) | (bx >> 3)) * 64;   // XCD swizzle

    const int tid  = threadIdx.x;
    const int wid  = tid >> 6, lane = tid & 63;
    const int l16  = lane & 15, quad = lane >> 4;

    bf16x8 qf[16];
    {
        const u16* qp = src + (size_t)(r0 + wid*16 + l16) * DPAD + quad*8;
#pragma unroll
        for (int kc = 0; kc < 16; ++kc) qf[kc] = *(const bf16x8*)(qp + kc*32);
    }

    f32x4 O[32];
#pragma unroll
    for (int i = 0; i < 32; ++i) O[i] = (f32x4){0.f, 0.f, 0.f, 0.f};
    f32x4 O2 = {0.f, 0.f, 0.f, 0.f};       // row sums via ones-MFMA

    bf16x8 ones8;
#pragma unroll
    for (int i = 0; i < 8; ++i) ones8[i] = (short)0x3F80;   // bf16 1.0

    const int kb_hi = (r0 >> 5) + 1;
    const int kb_lo = (kb_hi >= WTILES) ? kb_hi - (WTILES-1) : 0;

    {
        const u16* gK = src + (size_t)kb_lo * 32 * DPAD;
        for (int i = wid; i < 33; i += 4) dma16(gK + i*512 + lane*8, Ks + i*512);
    }

    for (int kb = kb_lo; kb <= kb_hi; ++kb) {
        __syncthreads();
        {
            const u16* gV = srcT + (size_t)kb * (DCH*32);
            for (int i = wid; i < 32; i += 4) dma16(gV + i*512 + lane*8, Vs + i*512);
        }

        f32x4 S0a = {0.f,0.f,0.f,0.f}, S1a = {0.f,0.f,0.f,0.f};
        f32x4 S0b = {0.f,0.f,0.f,0.f}, S1b = {0.f,0.f,0.f,0.f};
#pragma unroll
        for (int kc = 0; kc < 8; ++kc) {
            bf16x8 b0 = *(const bf16x8*)(Ks + (size_t)l16*DPAD + kc*32 + quad*8);
            bf16x8 b1 = *(const bf16x8*)(Ks + (size_t)(16+l16)*DPAD + kc*32 + quad*8);
            S0a = __builtin_amdgcn_mfma_f32_16x16x32_bf16(qf[kc], b0, S0a, 0, 0, 0);
            S1a = __builtin_amdgcn_mfma_f32_16x16x32_bf16(qf[kc], b1, S1a, 0, 0, 0);
        }
#pragma unroll
        for (int kc = 8; kc < 16; ++kc) {
            bf16x8 b0 = *(const bf16x8*)(Ks + (size_t)l16*DPAD + kc*32 + quad*8);
            bf16x8 b1 = *(const bf16x8*)(Ks + (size_t)(16+l16)*DPAD + kc*32 + quad*8);
            S0b = __builtin_amdgcn_mfma_f32_16x16x32_bf16(qf[kc], b0, S0b, 0, 0, 0);
            S1b = __builtin_amdgcn_mfma_f32_16x16x32_bf16(qf[kc], b1, S1b, 0, 0, 0);
        }
        f32x4 S0 = S0a + S0b, S1 = S1a + S1b;

        const int rowg = r0 + wid*16 + quad*4;
#pragma unroll
        for (int r = 0; r < 4; ++r) {
            int row = rowg + r;
            int d0  = row - (kb*32 + l16);
            int d1  = d0 - 16;
            float p0 = (d0 >= 0) ? __expf(fmaf(-DECAYF, (float)d0, S0[r] - 1.f)) : 0.f;
            float p1 = (d1 >= 0) ? __expf(fmaf(-DECAYF, (float)d1, S1[r] - 1.f)) : 0.f;
            Ps32[wid][quad*4 + r][l16] = ((unsigned)f2bf(p1) << 16) | (unsigned)f2bf(p0);
        }

        __syncthreads();
        if (kb < kb_hi) {
            const u16* gK = src + (size_t)(kb+1) * 32 * DPAD;
            for (int i = wid; i < 33; i += 4) dma16(gK + i*512 + lane*8, Ks + i*512);
        }

        bf16x8 pf = *(const bf16x8*)(&Ps32[wid][l16][quad*4]);
#pragma unroll
        for (int ct = 0; ct < 32; ++ct) {
            bf16x8 vf = *(const bf16x8*)(Vs + (size_t)(ct*16 + l16)*32 + quad*8);
            O[ct] = __builtin_amdgcn_mfma_f32_16x16x32_bf16(pf, vf, O[ct], 0, 0, 0);
        }
        O2 = __builtin_amdgcn_mfma_f32_16x16x32_bf16(pf, ones8, O2, 0, 0, 0);
    }

    float inv[4];
#pragma unroll
    for (int r = 0; r < 4; ++r) inv[r] = 1.f / O2[r];
    const size_t rowbase = (size_t)n * LSEQ + r0 + wid*16 + quad*4;
    const int colbase = t * 512 + l16;
#pragma unroll
    for (int ct = 0; ct < 32; ++ct) {
#pragma unroll
        for (int r = 0; r < 4; ++r)
            cat[(rowbase + r) * 1024 + colbase + ct*16] = f2bf(O[ct][r] * inv[r]);
    }
}

// ---------------------------------------------------------------------------
// Kernel 3: cast fusion_w fp32 -> bf16 (once; removes convert from GEMM loop)
// ---------------------------------------------------------------------------
__global__ __launch_bounds__(256) void cast_w(const float* __restrict__ w, u16* __restrict__ wb)
{
    int id = blockIdx.x * 256 + threadIdx.x;   // 131072 float4 chunks
    float4 f = ((const float4*)w)[id];
    u16x4 o;
    o[0] = f2bf(f.x); o[1] = f2bf(f.y); o[2] = f2bf(f.z); o[3] = f2bf(f.w);
    ((u16x4*)wb)[id] = o;
}

// ---------------------------------------------------------------------------
// Kernel 4: out[16384,512] = cat @ W^T + bias. 64x128 tiles, BK=64,
// dma16 staging with XOR-swizzled chunk mapping (swizzle via source addr:
// physical chunk kp holds logical k = kp ^ (row&7)) -> conflict-free b128.
// ---------------------------------------------------------------------------
__global__ __launch_bounds__(256) void fusion_gemm(
    const u16* __restrict__ A, const u16* __restrict__ Wb,
    const float* __restrict__ bias, float* __restrict__ out)
{
    __shared__ u16 As[64*64];    // 8 KB
    __shared__ u16 Bs[128*64];   // 16 KB
    const int m0 = blockIdx.x * 64;
    const int n0 = blockIdx.y * 128;
    const int tid = threadIdx.x;
    const int wid = tid >> 6, lane = tid & 63;
    const int l16 = lane & 15, quad = lane >> 4;

    f32x4 acc[4][2];
#pragma unroll
    for (int i = 0; i < 4; ++i)
#pragma unroll
        for (int j = 0; j < 2; ++j) acc[i][j] = (f32x4){0.f, 0.f, 0.f, 0.f};

    for (int kb = 0; kb < 16; ++kb) {
        __syncthreads();
        // A tile: 512 chunks of 16B
#pragma unroll
        for (int i = 0; i < 2; ++i) {
            int q = i*256 + tid, r = q >> 3, kp = q & 7;
            int kl = kp ^ (r & 7);
            dma16(A + (size_t)(m0 + r)*1024 + kb*64 + kl*8, As + q*8);
        }
        // W tile: 1024 chunks
#pragma unroll
        for (int i = 0; i < 4; ++i) {
            int q = i*256 + tid, r = q >> 3, kp = q & 7;
            int kl = kp ^ (r & 7);
            dma16(Wb + (size_t)(n0 + r)*1024 + kb*64 + kl*8, Bs + q*8);
        }
        __syncthreads();
#pragma unroll
        for (int k2 = 0; k2 < 2; ++k2) {
            const int kl = k2*4 + quad;
            bf16x8 af[4], bf2[2];
#pragma unroll
            for (int i = 0; i < 4; ++i) {
                int r = i*16 + l16;
                af[i] = *(const bf16x8*)(As + r*64 + (kl ^ (r & 7))*8);
            }
#pragma unroll
            for (int j = 0; j < 2; ++j) {
                int r = wid*32 + j*16 + l16;
                bf2[j] = *(const bf16x8*)(Bs + r*64 + (kl ^ (r & 7))*8);
            }
#pragma unroll
            for (int i = 0; i < 4; ++i)
#pragma unroll
                for (int j = 0; j < 2; ++j)
                    acc[i][j] = __builtin_amdgcn_mfma_f32_16x16x32_bf16(af[i], bf2[j], acc[i][j], 0, 0, 0);
        }
    }
#pragma unroll
    for (int j = 0; j < 2; ++j) {
        int col = n0 + wid*32 + j*16 + l16;
        float bv = bias[col];
#pragma unroll
        for (int i = 0; i < 4; ++i) {
            int rowb = m0 + i*16 + quad*4;
#pragma unroll
            for (int r = 0; r < 4; ++r)
                out[(size_t)(rowb + r)*512 + col] = acc[i][j][r] + bv;
        }
    }
}

// ---------------------------------------------------------------------------
extern "C" void kernel_launch(void* const* d_in, const int* in_sizes, int n_in,
                              void* d_out, int out_size, void* d_ws, size_t ws_size,
                              hipStream_t stream)
{
    (void)in_sizes; (void)n_in; (void)out_size; (void)ws_size;
    const float* x  = (const float*)d_in[0];
    const float* w3 = (const float*)d_in[1];
    const float* w5 = (const float*)d_in[2];
    const float* fw = (const float*)d_in[3];
    const float* fb = (const float*)d_in[4];
    float* out = (float*)d_out;

    const size_t SZP = (size_t)NBATCH * LSEQ * DPAD;    // padded rows
    const size_t SZT = (size_t)NBATCH * 64 * DCH * 32;  // V tiles
    u16* vs   = (u16*)d_ws;        // [N][L][520]
    u16* vt   = vs   + SZP;
    u16* vsTt = vt   + SZP;        // [N][64][512][32] (interleaved keys)
    u16* vtTt = vsTt + SZT;
    u16* cat  = vtTt + SZT;        // [N*L][1024]
    u16* wb   = cat  + (size_t)NBATCH*LSEQ*1024;   // [512][1024] bf16

    cast_w     <<<512, 256, 0, stream>>>(fw, wb);
    conv_route <<<512, 512, 0, stream>>>(x, w3, w5, vs, vt, vsTt, vtTt);
    attn       <<<dim3(32, 16), 256, 0, stream>>>(vs, vt, vsTt, vtTt, cat);
    fusion_gemm<<<dim3(256, 4), 256, 0, stream>>>(cat, wb, fb, out);
}

// Round 7
// 166.885 us; speedup vs baseline: 6.2238x; 1.0257x over previous
//
#include <hip/hip_runtime.h>

// ---------------------------------------------------------------------------
// capsule_87840671138361: conv->routing->attention->fusion, MI355X (gfx950)
// R7 changes vs R6:
//  - attn: V^T built IN-KERNEL from Ks (K rows == V rows) via LDS->LDS
//    transpose once per tile; V-DMA + global vsTt/vtTt buffers DELETED
//    (-67 MB HBM traffic, -1 kernel's worth of work in conv).
//  - Vs row stride 40 u16 (allowed now: no DMA into Vs) -> bank-even b128
//    reads (Phase B) and writes (transpose); old stride-32 was the 3.1M
//    bank-conflict source (lanes 0-7 span starts {0,16} = 4-way).
//  - conv_route reverted to R5 wave-per-position form (no LDS, no serial
//    4-position chain, full TLP); writes only padded vs/vt rows.
//  - fusion_gemm / cast_w unchanged from R6.
// ---------------------------------------------------------------------------

typedef short     bf16x8 __attribute__((ext_vector_type(8)));  // MFMA A/B frag
typedef float     f32x4  __attribute__((ext_vector_type(4)));  // MFMA C/D frag
typedef unsigned short u16;
typedef u16       u16x8  __attribute__((ext_vector_type(8)));
typedef u16       u16x4  __attribute__((ext_vector_type(4)));

#define NBATCH 8
#define LSEQ   2048
#define DCH    512
#define DPAD   520      // padded global row stride (elems): 1040B
#define VSTR   40       // Vs LDS row stride (u16): 80B -> bank-even b128
#define DECAYF 0.2f
#define WTILES 4        // 64-key min window; truncated mass ~4e-5 relative

typedef const __attribute__((address_space(1))) unsigned char* gas_t;
typedef __attribute__((address_space(3))) unsigned char* las_t;
__device__ __forceinline__ void dma16(const void* g, void* l) {
    __builtin_amdgcn_global_load_lds((gas_t)g, (las_t)l, 16, 0, 0);
}

__device__ __forceinline__ u16 f2bf(float f) {
    unsigned int u = __float_as_uint(f);
    u += 0x7fffu + ((u >> 16) & 1u);   // RNE; inputs never NaN
    return (u16)(u >> 16);
}

__device__ __forceinline__ void wave_sum6(float& a, float& b, float& c,
                                          float& d, float& e, float& f) {
#pragma unroll
    for (int m = 1; m < 64; m <<= 1) {
        float ta = __shfl_xor(a, m, 64);
        float tb = __shfl_xor(b, m, 64);
        float tc = __shfl_xor(c, m, 64);
        float td = __shfl_xor(d, m, 64);
        float te = __shfl_xor(e, m, 64);
        float tf = __shfl_xor(f, m, 64);
        a += ta; b += tb; c += tc; d += td; e += te; f += tf;
    }
}

// ---------------------------------------------------------------------------
// Kernel 1: causal depthwise conv (k=3,5) + 2x dynamic routing via Gram dots.
// One wave per (n,l); lane owns 8 channels. (R5 structure: full TLP, no LDS.)
// ---------------------------------------------------------------------------
__global__ __launch_bounds__(256) void conv_route(
    const float* __restrict__ x, const float* __restrict__ w3, const float* __restrict__ w5,
    u16* __restrict__ vs, u16* __restrict__ vt)
{
    const int wid  = threadIdx.x >> 6;
    const int lane = threadIdx.x & 63;
    const int p = blockIdx.x * 4 + wid;          // 16384 positions
    const int n = p >> 11, l = p & (LSEQ - 1);
    const int c0 = lane * 8;

    float xm[5][8];                              // xm[j][i] = x[l-j][c0+i]
#pragma unroll
    for (int j = 0; j < 5; ++j) {
        int ll = l - j;
        if (ll >= 0) {                           // wave-uniform branch
            const float4* sp = (const float4*)(x + ((size_t)(n*LSEQ + ll))*DCH + c0);
            float4 a = sp[0], b = sp[1];
            xm[j][0]=a.x; xm[j][1]=a.y; xm[j][2]=a.z; xm[j][3]=a.w;
            xm[j][4]=b.x; xm[j][5]=b.y; xm[j][6]=b.z; xm[j][7]=b.w;
        } else {
#pragma unroll
            for (int i = 0; i < 8; ++i) xm[j][i] = 0.f;
        }
    }
    float f3[24], f5[40];
#pragma unroll
    for (int k = 0; k < 6; ++k)  ((float4*)f3)[k] = ((const float4*)(w3 + (size_t)c0*3))[k];
#pragma unroll
    for (int k = 0; k < 10; ++k) ((float4*)f5)[k] = ((const float4*)(w5 + (size_t)c0*5))[k];

    float t3[8], t5[8], a0[8], a1[8];
#pragma unroll
    for (int i = 0; i < 8; ++i) {
        t3[i] = f3[i*3+0]*xm[2][i] + f3[i*3+1]*xm[1][i] + f3[i*3+2]*xm[0][i];
        t5[i] = f5[i*5+0]*xm[4][i] + f5[i*5+1]*xm[3][i] + f5[i*5+2]*xm[2][i]
              + f5[i*5+3]*xm[1][i] + f5[i*5+4]*xm[0][i];
        a0[i] = xm[0][i] - t3[i];
        a1[i] = xm[0][i] - t5[i];
    }

    float A1=0.f, B1=0.f, C1=0.f, A2=0.f, B2=0.f, C2=0.f;
#pragma unroll
    for (int i = 0; i < 8; ++i) {
        A1 += a0[i]*a0[i]; B1 += a0[i]*a1[i]; C1 += a1[i]*a1[i];
        A2 += t3[i]*t3[i]; B2 += t3[i]*t5[i]; C2 += t5[i]*t5[i];
    }
    wave_sum6(A1, B1, C1, A2, B2, C2);

    float ba0=0.f, ba1=0.f, bb0=0.f, bb1=0.f;
    float ca0=0.5f, ca1=0.5f, sca=0.f, cb0=0.5f, cb1=0.5f, scb=0.f;
#pragma unroll
    for (int it = 0; it < 3; ++it) {
        float mxa = fmaxf(ba0, ba1), mxb = fmaxf(bb0, bb1);
        float ea0 = __expf(ba0-mxa), ea1 = __expf(ba1-mxa);
        float eb0 = __expf(bb0-mxb), eb1 = __expf(bb1-mxb);
        float ia = 1.f/(ea0+ea1), ib = 1.f/(eb0+eb1);
        ca0 = ea0*ia; ca1 = ea1*ia; cb0 = eb0*ib; cb1 = eb1*ib;
        float na = ca0*ca0*A1 + 2.f*ca0*ca1*B1 + ca1*ca1*C1;
        float nb = cb0*cb0*A2 + 2.f*cb0*cb1*B2 + cb1*cb1*C2;
        sca = na / ((1.f + na) * (sqrtf(na) + 1e-9f));
        scb = nb / ((1.f + nb) * (sqrtf(nb) + 1e-9f));
        if (it < 2) {
            ba0 += sca*(ca0*A1 + ca1*B1);
            ba1 += sca*(ca0*B1 + ca1*C1);
            bb0 += scb*(cb0*A2 + cb1*B2);
            bb1 += scb*(cb0*B2 + cb1*C2);
        }
    }
    u16x8 pa, pb;
#pragma unroll
    for (int i = 0; i < 8; ++i) {
        pa[i] = f2bf(sca*(ca0*a0[i] + ca1*a1[i]));
        pb[i] = f2bf(scb*(cb0*t3[i] + cb1*t5[i]));
    }
    *(u16x8*)(vs + (size_t)p*DPAD + c0) = pa;
    *(u16x8*)(vt + (size_t)p*DPAD + c0) = pb;
}

// ---------------------------------------------------------------------------
// Kernel 2: windowed causal attention; V^T built in-LDS from Ks.
// grid (32 strips, 16 instances), 256 threads (4 waves), 64 q-rows/block.
// ---------------------------------------------------------------------------
__global__ __launch_bounds__(256) void attn(
    const u16* __restrict__ vs, const u16* __restrict__ vt,
    u16* __restrict__ cat)
{
    __shared__ u16 Ks[33792/2];              // 32 rows x 1040B + DMA slack
    __shared__ u16 Vs[DCH*VSTR];             // 40 KB, [ch][40] slot-interleaved
    __shared__ unsigned int Ps32[4][16][20]; // per-wave P, packed pairs

    const int inst = blockIdx.y;
    const int t = inst >> 3, n = inst & 7;
    const u16* src = (t ? vt : vs) + (size_t)n * LSEQ * DPAD;

    const int bx = blockIdx.x;
    const int r0 = (((bx & 7) << 2) | (bx >> 3)) * 64;   // XCD swizzle

    const int tid  = threadIdx.x;
    const int wid  = tid >> 6, lane = tid & 63;
    const int l16  = lane & 15, quad = lane >> 4;

    // Q A-frags register-resident
    bf16x8 qf[16];
    {
        const u16* qp = src + (size_t)(r0 + wid*16 + l16) * DPAD + quad*8;
#pragma unroll
        for (int kc = 0; kc < 16; ++kc) qf[kc] = *(const bf16x8*)(qp + kc*32);
    }

    f32x4 O[32];
#pragma unroll
    for (int i = 0; i < 32; ++i) O[i] = (f32x4){0.f, 0.f, 0.f, 0.f};
    f32x4 O2 = {0.f, 0.f, 0.f, 0.f};       // row sums via ones-MFMA

    bf16x8 ones8;
#pragma unroll
    for (int i = 0; i < 8; ++i) ones8[i] = (short)0x3F80;   // bf16 1.0

    const int kb_hi = (r0 >> 5) + 1;
    const int kb_lo = (kb_hi >= WTILES) ? kb_hi - (WTILES-1) : 0;

    // prologue: K(kb_lo) in flight
    {
        const u16* gK = src + (size_t)kb_lo * 32 * DPAD;
        for (int i = wid; i < 33; i += 4) dma16(gK + i*512 + lane*8, Ks + i*512);
    }

    for (int kb = kb_lo; kb <= kb_hi; ++kb) {
        __syncthreads();   // K(kb) drained; prev Phase B done with Vs

        // Phase A: S[16x32] = Q * K^T, 4 independent 8-deep chains
        f32x4 S0a = {0.f,0.f,0.f,0.f}, S1a = {0.f,0.f,0.f,0.f};
        f32x4 S0b = {0.f,0.f,0.f,0.f}, S1b = {0.f,0.f,0.f,0.f};
#pragma unroll
        for (int kc = 0; kc < 8; ++kc) {
            bf16x8 b0 = *(const bf16x8*)(Ks + (size_t)l16*DPAD + kc*32 + quad*8);
            bf16x8 b1 = *(const bf16x8*)(Ks + (size_t)(16+l16)*DPAD + kc*32 + quad*8);
            S0a = __builtin_amdgcn_mfma_f32_16x16x32_bf16(qf[kc], b0, S0a, 0, 0, 0);
            S1a = __builtin_amdgcn_mfma_f32_16x16x32_bf16(qf[kc], b1, S1a, 0, 0, 0);
        }
#pragma unroll
        for (int kc = 8; kc < 16; ++kc) {
            bf16x8 b0 = *(const bf16x8*)(Ks + (size_t)l16*DPAD + kc*32 + quad*8);
            bf16x8 b1 = *(const bf16x8*)(Ks + (size_t)(16+l16)*DPAD + kc*32 + quad*8);
            S0b = __builtin_amdgcn_mfma_f32_16x16x32_bf16(qf[kc], b0, S0b, 0, 0, 0);
            S1b = __builtin_amdgcn_mfma_f32_16x16x32_bf16(qf[kc], b1, S1b, 0, 0, 0);
        }
        f32x4 S0 = S0a + S0b, S1 = S1a + S1b;

        // in-LDS transpose: Ks rows -> Vs[ch][40], slot s <- key (s>>1)+16(s&1)
        // reads: lanes=consecutive ch -> bank-distinct; writes: b128, 8-lane
        // phases hit 8 distinct span starts (stride 20 dwords).
#pragma unroll
        for (int pass = 0; pass < 2; ++pass) {
            const int ch = pass*256 + tid;
#pragma unroll
            for (int g = 0; g < 4; ++g) {
                u16x8 o;
#pragma unroll
                for (int j = 0; j < 4; ++j) {
                    o[2*j]   = Ks[(size_t)(g*4 + j)      * DPAD + ch];
                    o[2*j+1] = Ks[(size_t)(g*4 + j + 16) * DPAD + ch];
                }
                *(u16x8*)(Vs + ch*VSTR + g*8) = o;
            }
        }

        // fixed-max softmax: p = exp(s - 1 - 0.2*d), zero outside causal window
        const int rowg = r0 + wid*16 + quad*4;
#pragma unroll
        for (int r = 0; r < 4; ++r) {
            int row = rowg + r;
            int d0  = row - (kb*32 + l16);
            int d1  = d0 - 16;
            float p0 = (d0 >= 0) ? __expf(fmaf(-DECAYF, (float)d0, S0[r] - 1.f)) : 0.f;
            float p1 = (d1 >= 0) ? __expf(fmaf(-DECAYF, (float)d1, S1[r] - 1.f)) : 0.f;
            Ps32[wid][quad*4 + r][l16] = ((unsigned)f2bf(p1) << 16) | (unsigned)f2bf(p0);
        }

        __syncthreads();   // Vs complete; all waves done with Ks
        // K(kb+1) DMA overlaps Phase B
        if (kb < kb_hi) {
            const u16* gK = src + (size_t)(kb+1) * 32 * DPAD;
            for (int i = wid; i < 33; i += 4) dma16(gK + i*512 + lane*8, Ks + i*512);
        }

        // Phase B: O += P * V (slot-interleaved, consistent in Ps & Vs)
        bf16x8 pf = *(const bf16x8*)(&Ps32[wid][l16][quad*4]);
#pragma unroll
        for (int ct = 0; ct < 32; ++ct) {
            bf16x8 vf = *(const bf16x8*)(Vs + (size_t)(ct*16 + l16)*VSTR + quad*8);
            O[ct] = __builtin_amdgcn_mfma_f32_16x16x32_bf16(pf, vf, O[ct], 0, 0, 0);
        }
        O2 = __builtin_amdgcn_mfma_f32_16x16x32_bf16(pf, ones8, O2, 0, 0, 0);
    }

    // epilogue: O /= rowsum, write bf16 into cat
    float inv[4];
#pragma unroll
    for (int r = 0; r < 4; ++r) inv[r] = 1.f / O2[r];
    const size_t rowbase = (size_t)n * LSEQ + r0 + wid*16 + quad*4;
    const int colbase = t * 512 + l16;
#pragma unroll
    for (int ct = 0; ct < 32; ++ct) {
#pragma unroll
        for (int r = 0; r < 4; ++r)
            cat[(rowbase + r) * 1024 + colbase + ct*16] = f2bf(O[ct][r] * inv[r]);
    }
}

// ---------------------------------------------------------------------------
// Kernel 3: cast fusion_w fp32 -> bf16
// ---------------------------------------------------------------------------
__global__ __launch_bounds__(256) void cast_w(const float* __restrict__ w, u16* __restrict__ wb)
{
    int id = blockIdx.x * 256 + threadIdx.x;   // 131072 float4 chunks
    float4 f = ((const float4*)w)[id];
    u16x4 o;
    o[0] = f2bf(f.x); o[1] = f2bf(f.y); o[2] = f2bf(f.z); o[3] = f2bf(f.w);
    ((u16x4*)wb)[id] = o;
}

// ---------------------------------------------------------------------------
// Kernel 4: out[16384,512] = cat @ W^T + bias. 64x128 tiles, BK=64,
// dma16 staging with XOR-swizzled chunk mapping (swizzle via source addr).
// ---------------------------------------------------------------------------
__global__ __launch_bounds__(256) void fusion_gemm(
    const u16* __restrict__ A, const u16* __restrict__ Wb,
    const float* __restrict__ bias, float* __restrict__ out)
{
    __shared__ u16 As[64*64];    // 8 KB
    __shared__ u16 Bs[128*64];   // 16 KB
    const int m0 = blockIdx.x * 64;
    const int n0 = blockIdx.y * 128;
    const int tid = threadIdx.x;
    const int wid = tid >> 6, lane = tid & 63;
    const int l16 = lane & 15, quad = lane >> 4;

    f32x4 acc[4][2];
#pragma unroll
    for (int i = 0; i < 4; ++i)
#pragma unroll
        for (int j = 0; j < 2; ++j) acc[i][j] = (f32x4){0.f, 0.f, 0.f, 0.f};

    for (int kb = 0; kb < 16; ++kb) {
        __syncthreads();
#pragma unroll
        for (int i = 0; i < 2; ++i) {
            int q = i*256 + tid, r = q >> 3, kp = q & 7;
            int kl = kp ^ (r & 7);
            dma16(A + (size_t)(m0 + r)*1024 + kb*64 + kl*8, As + q*8);
        }
#pragma unroll
        for (int i = 0; i < 4; ++i) {
            int q = i*256 + tid, r = q >> 3, kp = q & 7;
            int kl = kp ^ (r & 7);
            dma16(Wb + (size_t)(n0 + r)*1024 + kb*64 + kl*8, Bs + q*8);
        }
        __syncthreads();
#pragma unroll
        for (int k2 = 0; k2 < 2; ++k2) {
            const int kl = k2*4 + quad;
            bf16x8 af[4], bf2[2];
#pragma unroll
            for (int i = 0; i < 4; ++i) {
                int r = i*16 + l16;
                af[i] = *(const bf16x8*)(As + r*64 + (kl ^ (r & 7))*8);
            }
#pragma unroll
            for (int j = 0; j < 2; ++j) {
                int r = wid*32 + j*16 + l16;
                bf2[j] = *(const bf16x8*)(Bs + r*64 + (kl ^ (r & 7))*8);
            }
#pragma unroll
            for (int i = 0; i < 4; ++i)
#pragma unroll
                for (int j = 0; j < 2; ++j)
                    acc[i][j] = __builtin_amdgcn_mfma_f32_16x16x32_bf16(af[i], bf2[j], acc[i][j], 0, 0, 0);
        }
    }
#pragma unroll
    for (int j = 0; j < 2; ++j) {
        int col = n0 + wid*32 + j*16 + l16;
        float bv = bias[col];
#pragma unroll
        for (int i = 0; i < 4; ++i) {
            int rowb = m0 + i*16 + quad*4;
#pragma unroll
            for (int r = 0; r < 4; ++r)
                out[(size_t)(rowb + r)*512 + col] = acc[i][j][r] + bv;
        }
    }
}

// ---------------------------------------------------------------------------
extern "C" void kernel_launch(void* const* d_in, const int* in_sizes, int n_in,
                              void* d_out, int out_size, void* d_ws, size_t ws_size,
                              hipStream_t stream)
{
    (void)in_sizes; (void)n_in; (void)out_size; (void)ws_size;
    const float* x  = (const float*)d_in[0];
    const float* w3 = (const float*)d_in[1];
    const float* w5 = (const float*)d_in[2];
    const float* fw = (const float*)d_in[3];
    const float* fb = (const float*)d_in[4];
    float* out = (float*)d_out;

    const size_t SZP = (size_t)NBATCH * LSEQ * DPAD;    // padded rows
    u16* vs   = (u16*)d_ws;        // [N][L][520]
    u16* vt   = vs   + SZP;
    u16* cat  = vt   + SZP;        // [N*L][1024]
    u16* wb   = cat  + (size_t)NBATCH*LSEQ*1024;   // [512][1024] bf16

    cast_w     <<<512, 256, 0, stream>>>(fw, wb);
    conv_route <<<4096, 256, 0, stream>>>(x, w3, w5, vs, vt);
    attn       <<<dim3(32, 16), 256, 0, stream>>>(vs, vt, cat);
    fusion_gemm<<<dim3(256, 4), 256, 0, stream>>>(cat, wb, fb, out);
}